// Round 3
// baseline (1861.000 us; speedup 1.0000x reference)
//
#include <hip/hip_runtime.h>

// ============================ problem constants ============================
constexpr int cB = 8, cT = 1024, cD = 512, cNH = 8, cHD = 64, cH = 127, cK = 32;
constexpr int cM = cB * cT;  // 8192 token rows
constexpr float cEPS = 1e-5f;

__device__ __forceinline__ float sigm_(float x) { return 1.0f / (1.0f + __expf(-x)); }

// ============================ LayerNorm ============================
// one wave (64 lanes) per 512-wide row; block = 4 rows. Optional final mask_fill.
template<bool MASKOUT>
__global__ __launch_bounds__(256) void ln_kernel(
    const float* __restrict__ in, const float* __restrict__ gw,
    const float* __restrict__ bw, const unsigned char* __restrict__ mask,
    float* __restrict__ out) {
  int row = blockIdx.x * 4 + (threadIdx.x >> 6);
  int lane = threadIdx.x & 63;
  const float4* x4 = reinterpret_cast<const float4*>(in + (size_t)row * cD);
  float4 v0 = x4[lane];
  float4 v1 = x4[lane + 64];
  float s = v0.x + v0.y + v0.z + v0.w + v1.x + v1.y + v1.z + v1.w;
  float q = v0.x * v0.x + v0.y * v0.y + v0.z * v0.z + v0.w * v0.w +
            v1.x * v1.x + v1.y * v1.y + v1.z * v1.z + v1.w * v1.w;
#pragma unroll
  for (int m = 1; m < 64; m <<= 1) {
    s += __shfl_xor(s, m);
    q += __shfl_xor(q, m);
  }
  float mean = s * (1.0f / cD);
  float var = q * (1.0f / cD) - mean * mean;
  float rs = rsqrtf(var + cEPS);
  float keep = 1.0f;
  if (MASKOUT) keep = mask[row] ? 0.0f : 1.0f;
  const float4* g4 = reinterpret_cast<const float4*>(gw);
  const float4* b4 = reinterpret_cast<const float4*>(bw);
  float4 ga = g4[lane], gb = g4[lane + 64];
  float4 ba = b4[lane], bb = b4[lane + 64];
  float4 o0, o1;
  o0.x = ((v0.x - mean) * rs * ga.x + ba.x) * keep;
  o0.y = ((v0.y - mean) * rs * ga.y + ba.y) * keep;
  o0.z = ((v0.z - mean) * rs * ga.z + ba.z) * keep;
  o0.w = ((v0.w - mean) * rs * ga.w + ba.w) * keep;
  o1.x = ((v1.x - mean) * rs * gb.x + bb.x) * keep;
  o1.y = ((v1.y - mean) * rs * gb.y + bb.y) * keep;
  o1.z = ((v1.z - mean) * rs * gb.z + bb.z) * keep;
  o1.w = ((v1.w - mean) * rs * gb.w + bb.w) * keep;
  float4* o4 = reinterpret_cast<float4*>(out + (size_t)row * cD);
  o4[lane] = o0;
  o4[lane + 64] = o1;
}

// ============================ fp32 GEMM ============================
// C[M,N] = act(A[M,K] @ W[K,N] + bias) [+ residual] [* mask]
// BM=128, BN=128, BK=16; 256 threads; 8x8 outputs/thread (cols split tn*4 / tn*4+64
// so each Ws ds_read_b128 is 2-way-bank at worst = free; Ws padded to 132 so the
// staging writes are 2-way as well).
// RES: 0 = none, 1 = res + v, 2 = res + 0.5*v
template<bool BIAS, bool SILU, int RES, bool MASK>
__global__ __launch_bounds__(256) void gemm_kernel(
    const float* __restrict__ A, const float* __restrict__ W,
    const float* __restrict__ bias, const float* res,
    const unsigned char* __restrict__ mask, float* out, int N, int K) {
  constexpr int BM = 128, BN = 128, BK = 16;
  constexpr int LDA = BM + 4;  // 132 words: 16B-aligned rows, conflict-free transpose store
  constexpr int LDW = BN + 4;  // 132 words: makes staging writes 2-way instead of 16-way
  __shared__ alignas(16) float As[BK][LDA];
  __shared__ alignas(16) float Ws[BK][LDW];
  const int tid = threadIdx.x;
  const int m0 = blockIdx.y * BM, n0 = blockIdx.x * BN;
  const int tm = tid >> 4, tn = tid & 15;  // 16x16 thread grid

  float acc[8][8] = {};

  // staging coordinates
  const int arow = tid >> 2, ac4 = (tid & 3) * 4;  // A: 2 x (64 rows x 4 float4)
  const int wrow = tid >> 4, wc = (tid & 15) * 8;  // W: 16 rows x (16 x 2 float4)
  const float* Ap0 = A + (size_t)(m0 + arow) * K + ac4;
  const float* Ap1 = A + (size_t)(m0 + arow + 64) * K + ac4;
  const float* Wp = W + (size_t)wrow * N + n0 + wc;

  for (int k0 = 0; k0 < K; k0 += BK) {
    float4 a0 = *reinterpret_cast<const float4*>(Ap0 + k0);
    float4 a1 = *reinterpret_cast<const float4*>(Ap1 + k0);
    float4 w0 = *reinterpret_cast<const float4*>(Wp + (size_t)k0 * N);
    float4 w1 = *reinterpret_cast<const float4*>(Wp + (size_t)k0 * N + 4);
    __syncthreads();
    As[ac4 + 0][arow] = a0.x;
    As[ac4 + 1][arow] = a0.y;
    As[ac4 + 2][arow] = a0.z;
    As[ac4 + 3][arow] = a0.w;
    As[ac4 + 0][arow + 64] = a1.x;
    As[ac4 + 1][arow + 64] = a1.y;
    As[ac4 + 2][arow + 64] = a1.z;
    As[ac4 + 3][arow + 64] = a1.w;
    *reinterpret_cast<float4*>(&Ws[wrow][wc]) = w0;
    *reinterpret_cast<float4*>(&Ws[wrow][wc + 4]) = w1;
    __syncthreads();
#pragma unroll
    for (int kk = 0; kk < BK; ++kk) {
      float4 xa0 = *reinterpret_cast<const float4*>(&As[kk][tm * 8]);
      float4 xa1 = *reinterpret_cast<const float4*>(&As[kk][tm * 8 + 4]);
      float4 xw0 = *reinterpret_cast<const float4*>(&Ws[kk][tn * 4]);
      float4 xw1 = *reinterpret_cast<const float4*>(&Ws[kk][tn * 4 + 64]);
      float av[8] = {xa0.x, xa0.y, xa0.z, xa0.w, xa1.x, xa1.y, xa1.z, xa1.w};
      float wv[8] = {xw0.x, xw0.y, xw0.z, xw0.w, xw1.x, xw1.y, xw1.z, xw1.w};
#pragma unroll
      for (int i = 0; i < 8; ++i)
#pragma unroll
        for (int j = 0; j < 8; ++j) acc[i][j] += av[i] * wv[j];
    }
  }

  const int c0 = n0 + tn * 4, c1 = n0 + tn * 4 + 64;
  float bv[8] = {0.f, 0.f, 0.f, 0.f, 0.f, 0.f, 0.f, 0.f};
  if (BIAS) {
    float4 ba = *reinterpret_cast<const float4*>(bias + c0);
    float4 bb = *reinterpret_cast<const float4*>(bias + c1);
    bv[0] = ba.x; bv[1] = ba.y; bv[2] = ba.z; bv[3] = ba.w;
    bv[4] = bb.x; bv[5] = bb.y; bv[6] = bb.z; bv[7] = bb.w;
  }
#pragma unroll
  for (int i = 0; i < 8; ++i) {
    int m = m0 + tm * 8 + i;
    float keep = 1.0f;
    if (MASK) keep = mask[m] ? 0.0f : 1.0f;
    float v[8];
#pragma unroll
    for (int j = 0; j < 8; ++j) {
      float t = acc[i][j] + bv[j];
      if (SILU) t = t * sigm_(t);
      int col = (j < 4) ? (c0 + j) : (c1 + j - 4);
      if (RES == 1) t = res[(size_t)m * N + col] + t;
      if (RES == 2) t = res[(size_t)m * N + col] + 0.5f * t;
      v[j] = t * keep;
    }
    float4 o0 = {v[0], v[1], v[2], v[3]};
    float4 o1 = {v[4], v[5], v[6], v[7]};
    *reinterpret_cast<float4*>(out + (size_t)m * N + c0) = o0;
    *reinterpret_cast<float4*>(out + (size_t)m * N + c1) = o1;
  }
}

// ============================ banded attention ============================
// one block = (b, h, 16 queries). Keys j in [q-127, q]. Scores include
// rel-pos bias (score = (q.k_j + q.rel[q-j]) / 8). K then V share one LDS buf.
__global__ __launch_bounds__(256) void attn_kernel(
    const float* __restrict__ qkv, const float* __restrict__ relpos,
    const unsigned char* __restrict__ mask, float* __restrict__ out) {
  constexpr int QT = 16, SL = 144, LDK = 68;  // 143 used slots, pad to 144; LDK breaks conflicts
  __shared__ alignas(16) float Qs[QT][cHD];
  __shared__ alignas(16) float KVs[SL][LDK];
  __shared__ alignas(16) float Ps[QT][SL];
  const int b = blockIdx.z, h = blockIdx.y, q0 = blockIdx.x * QT;
  const int tid = threadIdx.x;
  const size_t qkv_row = (size_t)3 * cD;

  {  // stage Q: 16 rows x 16 float4 == 256 threads
    int row = tid >> 4, d4 = (tid & 15) * 4;
    const float* src = qkv + (size_t)(b * cT + q0 + row) * qkv_row + h * cHD + d4;
    *reinterpret_cast<float4*>(&Qs[row][d4]) = *reinterpret_cast<const float4*>(src);
  }
  // stage K window: rows j = q0-127 .. q0+16
  for (int f = tid; f < SL * 16; f += 256) {
    int row = f >> 4, d4 = (f & 15) * 4;
    int j = q0 - cH + row;
    float4 v = {0.f, 0.f, 0.f, 0.f};
    if (j >= 0 && j < cT)
      v = *reinterpret_cast<const float4*>(qkv + (size_t)(b * cT + j) * qkv_row + cD + h * cHD + d4);
    *reinterpret_cast<float4*>(&KVs[row][d4]) = v;
  }
  __syncthreads();

  const int r = tid >> 4, c = tid & 15;  // 16 rows x 16 key-lanes
  float sc[9];
  float rowmax = -1e30f;
#pragma unroll
  for (int i = 0; i < 9; ++i) {
    int s = i * 16 + c;
    int j = q0 - cH + s;
    int pidx = cH + r - s;  // q - j
    float val = -1e30f;
    if (pidx >= 0 && pidx <= cH && j >= 0 && j < cT && !mask[(size_t)b * cT + j]) {
      const float4* q4 = reinterpret_cast<const float4*>(&Qs[r][0]);
      const float4* k4 = reinterpret_cast<const float4*>(&KVs[s][0]);
      const float4* r4 = reinterpret_cast<const float4*>(relpos + ((size_t)pidx * cNH + h) * cHD);
      float aK = 0.f, aR = 0.f;
#pragma unroll
      for (int d = 0; d < 16; ++d) {
        float4 qv = q4[d], kv = k4[d], rv = r4[d];
        aK += qv.x * kv.x + qv.y * kv.y + qv.z * kv.z + qv.w * kv.w;
        aR += qv.x * rv.x + qv.y * rv.y + qv.z * rv.z + qv.w * rv.w;
      }
      val = (aK + aR) * 0.125f;  // 1/sqrt(64)
    }
    sc[i] = val;
    rowmax = fmaxf(rowmax, val);
  }
#pragma unroll
  for (int m = 1; m < 16; m <<= 1) rowmax = fmaxf(rowmax, __shfl_xor(rowmax, m));
  float rsum = 0.f;
#pragma unroll
  for (int i = 0; i < 9; ++i) {
    float p = __expf(sc[i] - rowmax);
    sc[i] = p;
    rsum += p;
  }
#pragma unroll
  for (int m = 1; m < 16; m <<= 1) rsum += __shfl_xor(rsum, m);
  float inv = 1.0f / rsum;
#pragma unroll
  for (int i = 0; i < 9; ++i) Ps[r][i * 16 + c] = sc[i] * inv;
  __syncthreads();

  // stage V into the K buffer (K no longer needed)
  for (int f = tid; f < SL * 16; f += 256) {
    int row = f >> 4, d4 = (f & 15) * 4;
    int j = q0 - cH + row;
    float4 v = {0.f, 0.f, 0.f, 0.f};
    if (j >= 0 && j < cT)
      v = *reinterpret_cast<const float4*>(qkv + (size_t)(b * cT + j) * qkv_row + 2 * cD + h * cHD + d4);
    *reinterpret_cast<float4*>(&KVs[row][d4]) = v;
  }
  __syncthreads();

  // PV: thread (r,c) owns output dims d = 4c .. 4c+3 of query row r
  float4 acc = {0.f, 0.f, 0.f, 0.f};
  const int dc = c * 4;
  for (int s = 0; s < SL; ++s) {
    float p = Ps[r][s];
    float4 vv = *reinterpret_cast<const float4*>(&KVs[s][dc]);
    acc.x += p * vv.x;
    acc.y += p * vv.y;
    acc.z += p * vv.z;
    acc.w += p * vv.w;
  }
  *reinterpret_cast<float4*>(out + (size_t)(b * cT + q0 + r) * cD + h * cHD + dc) = acc;
}

// ============================ GLU + depthwise conv + BN + SiLU ============================
// grid (T/64, D/128, B); block 256 = 2 t-groups x 128 d-lanes.
__global__ __launch_bounds__(256) void dwconv_kernel(
    const float* __restrict__ pw1out, const float* __restrict__ dww,
    const float* __restrict__ dwb, const float* __restrict__ bng,
    const float* __restrict__ bnb, const float* __restrict__ bnm,
    const float* __restrict__ bnv, float* __restrict__ out) {
  constexpr int TT = 64, DD = 128, PAD = cK - 1;  // 31
  __shared__ alignas(16) float g_lds[TT + PAD][DD];
  const int b = blockIdx.z, d0 = blockIdx.y * DD, t0 = blockIdx.x * TT;
  const int tid = threadIdx.x;

  // stage GLU(a, g) for rows t0-31 .. t0+63
  for (int f = tid; f < (TT + PAD) * (DD / 4); f += 256) {
    int row = f >> 5, c4 = (f & 31) * 4;
    int t = t0 - PAD + row;
    float4 val = {0.f, 0.f, 0.f, 0.f};
    if (t >= 0) {
      const float* base = pw1out + (size_t)(b * cT + t) * (2 * cD) + d0 + c4;
      float4 a = *reinterpret_cast<const float4*>(base);
      float4 g = *reinterpret_cast<const float4*>(base + cD);
      val.x = a.x * sigm_(g.x);
      val.y = a.y * sigm_(g.y);
      val.z = a.z * sigm_(g.z);
      val.w = a.w * sigm_(g.w);
    }
    *reinterpret_cast<float4*>(&g_lds[row][c4]) = val;
  }
  __syncthreads();

  const int dl = tid & 127, tg = tid >> 7;
  const int d = d0 + dl;
  float w[cK];
  const float4* w4 = reinterpret_cast<const float4*>(dww + (size_t)d * cK);
#pragma unroll
  for (int i = 0; i < cK / 4; ++i) {
    float4 t4 = w4[i];
    w[i * 4 + 0] = t4.x; w[i * 4 + 1] = t4.y; w[i * 4 + 2] = t4.z; w[i * 4 + 3] = t4.w;
  }
  const float bias = dwb[d];
  const float scale = bng[d] * rsqrtf(bnv[d] + cEPS);
  const float shift = bnb[d] - bnm[d] * scale;
#pragma unroll 4
  for (int i = 0; i < 32; ++i) {
    int tl = tg * 32 + i;
    float acc = bias;
#pragma unroll
    for (int k = 0; k < cK; ++k) acc += w[k] * g_lds[tl + k][dl];
    float v = acc * scale + shift;
    v = v * sigm_(v);  // SiLU
    out[(size_t)(b * cT + t0 + tl) * cD + d] = v;
  }
}

// ============================ launch ============================
extern "C" void kernel_launch(void* const* d_in, const int* in_sizes, int n_in,
                              void* d_out, int out_size, void* d_ws, size_t ws_size,
                              hipStream_t stream) {
  const float* x = (const float*)d_in[0];
  const unsigned char* mask = (const unsigned char*)d_in[1];
  const float* ff1_ng = (const float*)d_in[2];
  const float* ff1_nb = (const float*)d_in[3];
  const float* ff1_w1 = (const float*)d_in[4];
  const float* ff1_b1 = (const float*)d_in[5];
  const float* ff1_w2 = (const float*)d_in[6];
  const float* ff1_b2 = (const float*)d_in[7];
  const float* mha_ng = (const float*)d_in[8];
  const float* mha_nb = (const float*)d_in[9];
  const float* wqkv = (const float*)d_in[10];
  const float* wout = (const float*)d_in[11];
  const float* bout = (const float*)d_in[12];
  const float* rel_pos = (const float*)d_in[13];
  const float* conv_ng = (const float*)d_in[14];
  const float* conv_nb = (const float*)d_in[15];
  const float* pw1_w = (const float*)d_in[16];
  const float* pw1_b = (const float*)d_in[17];
  const float* dw_w = (const float*)d_in[18];
  const float* dw_b = (const float*)d_in[19];
  const float* bn_g = (const float*)d_in[20];
  const float* bn_b = (const float*)d_in[21];
  const float* bn_m = (const float*)d_in[22];
  const float* bn_v = (const float*)d_in[23];
  const float* pw2_w = (const float*)d_in[24];
  const float* pw2_b = (const float*)d_in[25];
  const float* ff2_ng = (const float*)d_in[26];
  const float* ff2_nb = (const float*)d_in[27];
  const float* ff2_w1 = (const float*)d_in[28];
  const float* ff2_b1 = (const float*)d_in[29];
  const float* ff2_w2 = (const float*)d_in[30];
  const float* ff2_b2 = (const float*)d_in[31];
  const float* final_ng = (const float*)d_in[32];
  const float* final_nb = (const float*)d_in[33];

  float* X = (float*)d_out;  // residual stream lives in d_out
  float* ws = (float*)d_ws;
  float* lnb = ws;                  // [8192, 512]  16 MB
  float* aux = ws + 4194304;        // [8192, 512]  16 MB
  float* mid = ws + 8388608;        // [8192, 2048] 64 MB (ffn mid / qkv / pw1)

  const dim3 blk(256);
  const dim3 ln_grid(cM / 4);
  const dim3 g512(512 / 128, cM / 128);
  const dim3 g1024(1024 / 128, cM / 128);
  const dim3 g1536(1536 / 128, cM / 128);
  const dim3 g2048(2048 / 128, cM / 128);

  // ---- FFN1 ----  (residual = pristine input x)
  ln_kernel<false><<<ln_grid, blk, 0, stream>>>(x, ff1_ng, ff1_nb, nullptr, lnb);
  gemm_kernel<true, true, 0, false><<<g2048, blk, 0, stream>>>(lnb, ff1_w1, ff1_b1, nullptr, nullptr, mid, 2048, 512);
  gemm_kernel<true, false, 2, true><<<g512, blk, 0, stream>>>(mid, ff1_w2, ff1_b2, x, mask, X, 512, 2048);
  // ---- MHA ----  (residual = X)
  ln_kernel<false><<<ln_grid, blk, 0, stream>>>(X, mha_ng, mha_nb, nullptr, lnb);
  gemm_kernel<false, false, 0, false><<<g1536, blk, 0, stream>>>(lnb, wqkv, nullptr, nullptr, nullptr, mid, 1536, 512);
  attn_kernel<<<dim3(cT / 16, cNH, cB), blk, 0, stream>>>(mid, rel_pos, mask, aux);
  gemm_kernel<true, false, 1, true><<<g512, blk, 0, stream>>>(aux, wout, bout, X, mask, X, 512, 512);
  // ---- Conv module ----  (residual = X)
  ln_kernel<false><<<ln_grid, blk, 0, stream>>>(X, conv_ng, conv_nb, nullptr, lnb);
  gemm_kernel<true, false, 0, false><<<g1024, blk, 0, stream>>>(lnb, pw1_w, pw1_b, nullptr, nullptr, mid, 1024, 512);
  dwconv_kernel<<<dim3(cT / 64, cD / 128, cB), blk, 0, stream>>>(mid, dw_w, dw_b, bn_g, bn_b, bn_m, bn_v, aux);
  gemm_kernel<true, false, 1, true><<<g512, blk, 0, stream>>>(aux, pw2_w, pw2_b, X, mask, X, 512, 512);
  // ---- FFN2 ----  (residual = X, **was incorrectly `x` — the round-2 failure**)
  ln_kernel<false><<<ln_grid, blk, 0, stream>>>(X, ff2_ng, ff2_nb, nullptr, lnb);
  gemm_kernel<true, true, 0, false><<<g2048, blk, 0, stream>>>(lnb, ff2_w1, ff2_b1, nullptr, nullptr, mid, 2048, 512);
  gemm_kernel<true, false, 2, true><<<g512, blk, 0, stream>>>(mid, ff2_w2, ff2_b2, X, mask, X, 512, 2048);
  // ---- final LN (in-place on d_out) + mask ----
  ln_kernel<true><<<ln_grid, blk, 0, stream>>>(X, final_ng, final_nb, mask, X);
}

// Round 6
// 742.956 us; speedup vs baseline: 2.5049x; 2.5049x over previous
//
#include <hip/hip_runtime.h>

// ============================ problem constants ============================
constexpr int cB = 8, cT = 1024, cD = 512, cNH = 8, cHD = 64, cH = 127, cK = 32;
constexpr int cM = cB * cT;  // 8192 token rows
constexpr float cEPS = 1e-5f;

typedef __attribute__((ext_vector_type(8))) short bf16x8;
typedef __attribute__((ext_vector_type(4))) float f32x4;
typedef __attribute__((ext_vector_type(8))) unsigned short u16x8;

__device__ __forceinline__ float sigm_(float x) { return 1.0f / (1.0f + __expf(-x)); }

__device__ __forceinline__ unsigned short f2bf(float f) {
  union { float f; unsigned int u; } v; v.f = f;
  unsigned int r = v.u + 0x7fffu + ((v.u >> 16) & 1u);  // RNE
  return (unsigned short)(r >> 16);
}

__device__ __forceinline__ void gload_lds16(const void* g, void* l) {
  __builtin_amdgcn_global_load_lds(
      (const __attribute__((address_space(1))) void*)g,
      (__attribute__((address_space(3))) void*)l, 16, 0, 0);
}

// ============================ LayerNorm (fp32 in, bf16 or fp32 out) ============================
template<bool MASKOUT, bool OUTBF>
__global__ __launch_bounds__(256) void ln_kernel(
    const float* __restrict__ in, const float* __restrict__ gw,
    const float* __restrict__ bw, const unsigned char* __restrict__ mask,
    void* __restrict__ outv) {
  int row = blockIdx.x * 4 + (threadIdx.x >> 6);
  int lane = threadIdx.x & 63;
  const float4* x4 = reinterpret_cast<const float4*>(in + (size_t)row * cD);
  float4 v0 = x4[2 * lane];
  float4 v1 = x4[2 * lane + 1];
  float s = v0.x + v0.y + v0.z + v0.w + v1.x + v1.y + v1.z + v1.w;
  float q = v0.x * v0.x + v0.y * v0.y + v0.z * v0.z + v0.w * v0.w +
            v1.x * v1.x + v1.y * v1.y + v1.z * v1.z + v1.w * v1.w;
#pragma unroll
  for (int m = 1; m < 64; m <<= 1) {
    s += __shfl_xor(s, m);
    q += __shfl_xor(q, m);
  }
  float mean = s * (1.0f / cD);
  float var = q * (1.0f / cD) - mean * mean;
  float rs = rsqrtf(var + cEPS);
  float keep = 1.0f;
  if (MASKOUT) keep = mask[row] ? 0.0f : 1.0f;
  const float4* g4 = reinterpret_cast<const float4*>(gw);
  const float4* b4 = reinterpret_cast<const float4*>(bw);
  float4 ga = g4[2 * lane], gb = g4[2 * lane + 1];
  float4 ba = b4[2 * lane], bb = b4[2 * lane + 1];
  float o[8];
  o[0] = ((v0.x - mean) * rs * ga.x + ba.x) * keep;
  o[1] = ((v0.y - mean) * rs * ga.y + ba.y) * keep;
  o[2] = ((v0.z - mean) * rs * ga.z + ba.z) * keep;
  o[3] = ((v0.w - mean) * rs * ga.w + ba.w) * keep;
  o[4] = ((v1.x - mean) * rs * gb.x + bb.x) * keep;
  o[5] = ((v1.y - mean) * rs * gb.y + bb.y) * keep;
  o[6] = ((v1.z - mean) * rs * gb.z + bb.z) * keep;
  o[7] = ((v1.w - mean) * rs * gb.w + bb.w) * keep;
  if (OUTBF) {
    u16x8 p;
#pragma unroll
    for (int i = 0; i < 8; ++i) p[i] = f2bf(o[i]);
    *reinterpret_cast<u16x8*>((unsigned short*)outv + (size_t)row * cD + lane * 8) = p;
  } else {
    float4 o0 = {o[0], o[1], o[2], o[3]}, o1 = {o[4], o[5], o[6], o[7]};
    float4* o4 = reinterpret_cast<float4*>((float*)outv + (size_t)row * cD);
    o4[2 * lane] = o0;
    o4[2 * lane + 1] = o1;
  }
}

// ============================ weight fp32[K,N] -> bf16 W^T[N,K] ============================
__global__ __launch_bounds__(256) void wconv_kernel(
    const float* __restrict__ W, unsigned short* __restrict__ WT, int K, int N) {
  __shared__ float t[64][65];
  const int n0 = blockIdx.x * 64, k0 = blockIdx.y * 64;
  const int tx = threadIdx.x & 63, ty = threadIdx.x >> 6;
#pragma unroll
  for (int i = 0; i < 16; ++i) {
    int kr = ty * 16 + i;
    t[kr][tx] = W[(size_t)(k0 + kr) * N + n0 + tx];
  }
  __syncthreads();
#pragma unroll
  for (int i = 0; i < 16; ++i) {
    int nr = ty * 16 + i;
    WT[(size_t)(n0 + nr) * K + k0 + tx] = f2bf(t[tx][nr]);
  }
}

// ============================ bf16 MFMA GEMM (m97 structure, linear LDS) ============================
// C[M,N] = act(A[M,K]bf16 @ W[K,N] + bias) [+res] [*mask]; W given as WT[N,K]bf16.
// 128x128 tile, BK=32, 4 waves (2x2 of 64x64), mfma_f32_16x16x32_bf16.
// LDS tiles linear [128 rows][32 cols] bf16 (64B rows). NO swizzle: for 64B rows the
// fragment read (fr=lane&15 row, fq=lane>>4 chunk) already touches all 8 bank-quads
// = structural minimum; round-4's (row&7)<<4 swizzle overflowed the 64B row -> NaN.
template<bool BIAS, bool SILU, int RES, bool MASK, bool OUTBF>
__global__ __launch_bounds__(256) void mgemm_kernel(
    const unsigned short* __restrict__ A, const unsigned short* __restrict__ WT,
    const float* __restrict__ bias, const float* __restrict__ res,
    const unsigned char* __restrict__ mask, void* __restrict__ outv,
    int N, int K) {
  __shared__ unsigned short ldsA[4096];  // 128 x 32 bf16 = 8 KB
  __shared__ unsigned short ldsB[4096];
  const int tid = threadIdx.x, lane = tid & 63, wid = tid >> 6;
  const int m0 = blockIdx.y * 128, n0 = blockIdx.x * 128;
  const int wr = wid >> 1, wc = wid & 1;  // wave's 64x64 quadrant

  // ---- staging: each wave stages 32 rows of A and of B via 2 gload_lds each.
  // lane i of the wave writes LDS bytes [wave_base + i*16); its global source is
  // row sr = wid*32 + (i>>2), 16B chunk (i&3) of the current k-window (linear).
  const int sr = wid * 32 + (lane >> 2);
  const int sc = (lane & 3) * 8;  // element offset within k-window (8 bf16 = 16B)
  const unsigned short* a0 = A + (size_t)(m0 + sr) * K + sc;
  const unsigned short* a1 = A + (size_t)(m0 + sr + 16) * K + sc;
  const unsigned short* b0 = WT + (size_t)(n0 + sr) * K + sc;
  const unsigned short* b1 = WT + (size_t)(n0 + sr + 16) * K + sc;
  unsigned short* lA0 = ldsA + wid * 1024;  // row wid*32
  unsigned short* lA1 = lA0 + 512;          // row wid*32+16
  unsigned short* lB0 = ldsB + wid * 1024;
  unsigned short* lB1 = lB0 + 512;

  f32x4 acc[4][4] = {};

  const int fr = lane & 15, fq = lane >> 4;  // fragment row, k-chunk
  const int fco = fq * 8;                    // element col within 32-wide LDS row

  for (int k0 = 0; k0 < K; k0 += 32) {
    __syncthreads();  // previous tile fully consumed
    gload_lds16(a0 + k0, lA0);
    gload_lds16(a1 + k0, lA1);
    gload_lds16(b0 + k0, lB0);
    gload_lds16(b1 + k0, lB1);
    asm volatile("s_waitcnt vmcnt(0)" ::: "memory");
    __syncthreads();
    bf16x8 af[4], bfr[4];
#pragma unroll
    for (int f = 0; f < 4; ++f) {
      af[f] = *reinterpret_cast<const bf16x8*>(ldsA + (wr * 64 + f * 16 + fr) * 32 + fco);
      bfr[f] = *reinterpret_cast<const bf16x8*>(ldsB + (wc * 64 + f * 16 + fr) * 32 + fco);
    }
#pragma unroll
    for (int i = 0; i < 4; ++i)
#pragma unroll
      for (int j = 0; j < 4; ++j)
        acc[i][j] = __builtin_amdgcn_mfma_f32_16x16x32_bf16(af[i], bfr[j], acc[i][j], 0, 0, 0);
  }

  // ---- epilogue: lane holds D[fq*4+j][fr] of each 16x16 fragment
#pragma unroll
  for (int fm = 0; fm < 4; ++fm) {
#pragma unroll
    for (int fn = 0; fn < 4; ++fn) {
      const int cn = n0 + wc * 64 + fn * 16 + fr;
      const float bv = BIAS ? bias[cn] : 0.0f;
#pragma unroll
      for (int j = 0; j < 4; ++j) {
        const int m = m0 + wr * 64 + fm * 16 + fq * 4 + j;
        float t = acc[fm][fn][j] + bv;
        if (SILU) t = t * sigm_(t);
        if (RES == 1) t = res[(size_t)m * N + cn] + t;
        if (RES == 2) t = res[(size_t)m * N + cn] + 0.5f * t;
        if (MASK) t = mask[m] ? 0.0f : t;
        if (OUTBF) ((unsigned short*)outv)[(size_t)m * N + cn] = f2bf(t);
        else       ((float*)outv)[(size_t)m * N + cn] = t;
      }
    }
  }
}

// ============================ banded attention (fp32 in, bf16 out) ============================
__global__ __launch_bounds__(256) void attn_kernel(
    const float* __restrict__ qkv, const float* __restrict__ relpos,
    const unsigned char* __restrict__ mask, unsigned short* __restrict__ out) {
  constexpr int QT = 16, SL = 144, LDK = 68;
  __shared__ alignas(16) float Qs[QT][cHD];
  __shared__ alignas(16) float KVs[SL][LDK];
  __shared__ alignas(16) float Ps[QT][SL];
  const int b = blockIdx.z, h = blockIdx.y, q0 = blockIdx.x * QT;
  const int tid = threadIdx.x;
  const size_t qkv_row = (size_t)3 * cD;

  {
    int row = tid >> 4, d4 = (tid & 15) * 4;
    const float* src = qkv + (size_t)(b * cT + q0 + row) * qkv_row + h * cHD + d4;
    *reinterpret_cast<float4*>(&Qs[row][d4]) = *reinterpret_cast<const float4*>(src);
  }
  for (int f = tid; f < SL * 16; f += 256) {
    int row = f >> 4, d4 = (f & 15) * 4;
    int j = q0 - cH + row;
    float4 v = {0.f, 0.f, 0.f, 0.f};
    if (j >= 0 && j < cT)
      v = *reinterpret_cast<const float4*>(qkv + (size_t)(b * cT + j) * qkv_row + cD + h * cHD + d4);
    *reinterpret_cast<float4*>(&KVs[row][d4]) = v;
  }
  __syncthreads();

  const int r = tid >> 4, c = tid & 15;
  float sc[9];
  float rowmax = -1e30f;
#pragma unroll
  for (int i = 0; i < 9; ++i) {
    int s = i * 16 + c;
    int j = q0 - cH + s;
    int pidx = cH + r - s;
    float val = -1e30f;
    if (pidx >= 0 && pidx <= cH && j >= 0 && j < cT && !mask[(size_t)b * cT + j]) {
      const float4* q4 = reinterpret_cast<const float4*>(&Qs[r][0]);
      const float4* k4 = reinterpret_cast<const float4*>(&KVs[s][0]);
      const float4* r4 = reinterpret_cast<const float4*>(relpos + ((size_t)pidx * cNH + h) * cHD);
      float aK = 0.f, aR = 0.f;
#pragma unroll
      for (int d = 0; d < 16; ++d) {
        float4 qv = q4[d], kv = k4[d], rv = r4[d];
        aK += qv.x * kv.x + qv.y * kv.y + qv.z * kv.z + qv.w * kv.w;
        aR += qv.x * rv.x + qv.y * rv.y + qv.z * rv.z + qv.w * rv.w;
      }
      val = (aK + aR) * 0.125f;
    }
    sc[i] = val;
    rowmax = fmaxf(rowmax, val);
  }
#pragma unroll
  for (int m = 1; m < 16; m <<= 1) rowmax = fmaxf(rowmax, __shfl_xor(rowmax, m));
  float rsum = 0.f;
#pragma unroll
  for (int i = 0; i < 9; ++i) {
    float p = __expf(sc[i] - rowmax);
    sc[i] = p;
    rsum += p;
  }
#pragma unroll
  for (int m = 1; m < 16; m <<= 1) rsum += __shfl_xor(rsum, m);
  float inv = 1.0f / rsum;
#pragma unroll
  for (int i = 0; i < 9; ++i) Ps[r][i * 16 + c] = sc[i] * inv;
  __syncthreads();

  for (int f = tid; f < SL * 16; f += 256) {
    int row = f >> 4, d4 = (f & 15) * 4;
    int j = q0 - cH + row;
    float4 v = {0.f, 0.f, 0.f, 0.f};
    if (j >= 0 && j < cT)
      v = *reinterpret_cast<const float4*>(qkv + (size_t)(b * cT + j) * qkv_row + 2 * cD + h * cHD + d4);
    *reinterpret_cast<float4*>(&KVs[row][d4]) = v;
  }
  __syncthreads();

  float4 acc = {0.f, 0.f, 0.f, 0.f};
  const int dc = c * 4;
  for (int s = 0; s < SL; ++s) {
    float p = Ps[r][s];
    float4 vv = *reinterpret_cast<const float4*>(&KVs[s][dc]);
    acc.x += p * vv.x;
    acc.y += p * vv.y;
    acc.z += p * vv.z;
    acc.w += p * vv.w;
  }
  ushort4 o;
  o.x = f2bf(acc.x); o.y = f2bf(acc.y); o.z = f2bf(acc.z); o.w = f2bf(acc.w);
  *reinterpret_cast<ushort4*>(out + (size_t)(b * cT + q0 + r) * cD + h * cHD + dc) = o;
}

// ============================ GLU + depthwise conv + BN + SiLU (fp32 in, bf16 out) ============================
__global__ __launch_bounds__(256) void dwconv_kernel(
    const float* __restrict__ pw1out, const float* __restrict__ dww,
    const float* __restrict__ dwb, const float* __restrict__ bng,
    const float* __restrict__ bnb, const float* __restrict__ bnm,
    const float* __restrict__ bnv, unsigned short* __restrict__ out) {
  constexpr int TT = 64, DD = 128, PAD = cK - 1;
  __shared__ alignas(16) float g_lds[TT + PAD][DD];
  const int b = blockIdx.z, d0 = blockIdx.y * DD, t0 = blockIdx.x * TT;
  const int tid = threadIdx.x;

  for (int f = tid; f < (TT + PAD) * (DD / 4); f += 256) {
    int row = f >> 5, c4 = (f & 31) * 4;
    int t = t0 - PAD + row;
    float4 val = {0.f, 0.f, 0.f, 0.f};
    if (t >= 0) {
      const float* base = pw1out + (size_t)(b * cT + t) * (2 * cD) + d0 + c4;
      float4 a = *reinterpret_cast<const float4*>(base);
      float4 g = *reinterpret_cast<const float4*>(base + cD);
      val.x = a.x * sigm_(g.x);
      val.y = a.y * sigm_(g.y);
      val.z = a.z * sigm_(g.z);
      val.w = a.w * sigm_(g.w);
    }
    *reinterpret_cast<float4*>(&g_lds[row][c4]) = val;
  }
  __syncthreads();

  const int dl = tid & 127, tg = tid >> 7;
  const int d = d0 + dl;
  float w[cK];
  const float4* w4 = reinterpret_cast<const float4*>(dww + (size_t)d * cK);
#pragma unroll
  for (int i = 0; i < cK / 4; ++i) {
    float4 t4 = w4[i];
    w[i * 4 + 0] = t4.x; w[i * 4 + 1] = t4.y; w[i * 4 + 2] = t4.z; w[i * 4 + 3] = t4.w;
  }
  const float bias = dwb[d];
  const float scale = bng[d] * rsqrtf(bnv[d] + cEPS);
  const float shift = bnb[d] - bnm[d] * scale;
#pragma unroll 4
  for (int i = 0; i < 32; ++i) {
    int tl = tg * 32 + i;
    float acc = bias;
#pragma unroll
    for (int k = 0; k < cK; ++k) acc += w[k] * g_lds[tl + k][dl];
    float v = acc * scale + shift;
    v = v * sigm_(v);
    out[(size_t)(b * cT + t0 + tl) * cD + d] = f2bf(v);
  }
}

// ============================ launch ============================
extern "C" void kernel_launch(void* const* d_in, const int* in_sizes, int n_in,
                              void* d_out, int out_size, void* d_ws, size_t ws_size,
                              hipStream_t stream) {
  const float* x = (const float*)d_in[0];
  const unsigned char* mask = (const unsigned char*)d_in[1];
  const float* ff1_ng = (const float*)d_in[2];
  const float* ff1_nb = (const float*)d_in[3];
  const float* ff1_w1 = (const float*)d_in[4];
  const float* ff1_b1 = (const float*)d_in[5];
  const float* ff1_w2 = (const float*)d_in[6];
  const float* ff1_b2 = (const float*)d_in[7];
  const float* mha_ng = (const float*)d_in[8];
  const float* mha_nb = (const float*)d_in[9];
  const float* wqkv = (const float*)d_in[10];
  const float* wout = (const float*)d_in[11];
  const float* bout = (const float*)d_in[12];
  const float* rel_pos = (const float*)d_in[13];
  const float* conv_ng = (const float*)d_in[14];
  const float* conv_nb = (const float*)d_in[15];
  const float* pw1_w = (const float*)d_in[16];
  const float* pw1_b = (const float*)d_in[17];
  const float* dw_w = (const float*)d_in[18];
  const float* dw_b = (const float*)d_in[19];
  const float* bn_g = (const float*)d_in[20];
  const float* bn_b = (const float*)d_in[21];
  const float* bn_m = (const float*)d_in[22];
  const float* bn_v = (const float*)d_in[23];
  const float* pw2_w = (const float*)d_in[24];
  const float* pw2_b = (const float*)d_in[25];
  const float* ff2_ng = (const float*)d_in[26];
  const float* ff2_nb = (const float*)d_in[27];
  const float* ff2_w1 = (const float*)d_in[28];
  const float* ff2_b1 = (const float*)d_in[29];
  const float* ff2_w2 = (const float*)d_in[30];
  const float* ff2_b2 = (const float*)d_in[31];
  const float* final_ng = (const float*)d_in[32];
  const float* final_nb = (const float*)d_in[33];

  float* X = (float*)d_out;  // fp32 residual stream
  char* wsb = (char*)d_ws;
  unsigned short* lnb = (unsigned short*)wsb;                  // [8192,512] bf16, 8 MB
  unsigned short* auxb = (unsigned short*)(wsb + (8 << 20));   // [8192,512] bf16, 8 MB
  char* big = wsb + (16 << 20);                                // 48 MB: qkv f32 / ffn-mid bf16 / pw1out f32
  unsigned short* wT = (unsigned short*)(wsb + (64 << 20));    // 11.5 MB transposed bf16 weights
  float* bigf = (float*)big;
  unsigned short* bigh = (unsigned short*)big;

  unsigned short* wt_ff1w1 = wT + 0;        // [2048,512]
  unsigned short* wt_ff1w2 = wT + 1048576;  // [512,2048]
  unsigned short* wt_qkv   = wT + 2097152;  // [1536,512]
  unsigned short* wt_out   = wT + 2883584;  // [512,512]
  unsigned short* wt_pw1   = wT + 3145728;  // [1024,512]
  unsigned short* wt_pw2   = wT + 3670016;  // [512,512]
  unsigned short* wt_ff2w1 = wT + 3932160;  // [2048,512]
  unsigned short* wt_ff2w2 = wT + 4980736;  // [512,2048]

  const dim3 blk(256);
  const dim3 ln_grid(cM / 4);

  // ---- weight prep: fp32 [K,N] -> bf16 [N,K] ----
  wconv_kernel<<<dim3(2048 / 64, 512 / 64), blk, 0, stream>>>(ff1_w1, wt_ff1w1, 512, 2048);
  wconv_kernel<<<dim3(512 / 64, 2048 / 64), blk, 0, stream>>>(ff1_w2, wt_ff1w2, 2048, 512);
  wconv_kernel<<<dim3(1536 / 64, 512 / 64), blk, 0, stream>>>(wqkv, wt_qkv, 512, 1536);
  wconv_kernel<<<dim3(512 / 64, 512 / 64), blk, 0, stream>>>(wout, wt_out, 512, 512);
  wconv_kernel<<<dim3(1024 / 64, 512 / 64), blk, 0, stream>>>(pw1_w, wt_pw1, 512, 1024);
  wconv_kernel<<<dim3(512 / 64, 512 / 64), blk, 0, stream>>>(pw2_w, wt_pw2, 512, 512);
  wconv_kernel<<<dim3(2048 / 64, 512 / 64), blk, 0, stream>>>(ff2_w1, wt_ff2w1, 512, 2048);
  wconv_kernel<<<dim3(512 / 64, 2048 / 64), blk, 0, stream>>>(ff2_w2, wt_ff2w2, 2048, 512);

  // ---- FFN1 ----
  ln_kernel<false, true><<<ln_grid, blk, 0, stream>>>(x, ff1_ng, ff1_nb, nullptr, lnb);
  mgemm_kernel<true, true, 0, false, true><<<dim3(16, 64), blk, 0, stream>>>(
      lnb, wt_ff1w1, ff1_b1, nullptr, nullptr, bigh, 2048, 512);
  mgemm_kernel<true, false, 2, true, false><<<dim3(4, 64), blk, 0, stream>>>(
      bigh, wt_ff1w2, ff1_b2, x, mask, X, 512, 2048);
  // ---- MHA ----
  ln_kernel<false, true><<<ln_grid, blk, 0, stream>>>(X, mha_ng, mha_nb, nullptr, lnb);
  mgemm_kernel<false, false, 0, false, false><<<dim3(12, 64), blk, 0, stream>>>(
      lnb, wt_qkv, nullptr, nullptr, nullptr, bigf, 1536, 512);
  attn_kernel<<<dim3(cT / 16, cNH, cB), blk, 0, stream>>>(bigf, rel_pos, mask, auxb);
  mgemm_kernel<true, false, 1, true, false><<<dim3(4, 64), blk, 0, stream>>>(
      auxb, wt_out, bout, X, mask, X, 512, 512);
  // ---- Conv module ----
  ln_kernel<false, true><<<ln_grid, blk, 0, stream>>>(X, conv_ng, conv_nb, nullptr, lnb);
  mgemm_kernel<true, false, 0, false, false><<<dim3(8, 64), blk, 0, stream>>>(
      lnb, wt_pw1, pw1_b, nullptr, nullptr, bigf, 1024, 512);
  dwconv_kernel<<<dim3(cT / 64, cD / 128, cB), blk, 0, stream>>>(
      bigf, dw_w, dw_b, bn_g, bn_b, bn_m, bn_v, auxb);
  mgemm_kernel<true, false, 1, true, false><<<dim3(4, 64), blk, 0, stream>>>(
      auxb, wt_pw2, pw2_b, X, mask, X, 512, 512);
  // ---- FFN2 ----
  ln_kernel<false, true><<<ln_grid, blk, 0, stream>>>(X, ff2_ng, ff2_nb, nullptr, lnb);
  mgemm_kernel<true, true, 0, false, true><<<dim3(16, 64), blk, 0, stream>>>(
      lnb, wt_ff2w1, ff2_b1, nullptr, nullptr, bigh, 2048, 512);
  mgemm_kernel<true, false, 2, true, false><<<dim3(4, 64), blk, 0, stream>>>(
      bigh, wt_ff2w2, ff2_b2, X, mask, X, 512, 2048);
  // ---- final LN + mask (fp32 out, in-place) ----
  ln_kernel<true, false><<<ln_grid, blk, 0, stream>>>(X, final_ng, final_nb, mask, X);
}

// Round 7
// 520.850 us; speedup vs baseline: 3.5730x; 1.4264x over previous
//
#include <hip/hip_runtime.h>

// ============================ problem constants ============================
constexpr int cB = 8, cT = 1024, cD = 512, cNH = 8, cHD = 64, cH = 127, cK = 32;
constexpr int cM = cB * cT;  // 8192 token rows
constexpr float cEPS = 1e-5f;

typedef __attribute__((ext_vector_type(8))) short bf16x8;
typedef __attribute__((ext_vector_type(4))) float f32x4;
typedef __attribute__((ext_vector_type(8))) unsigned short u16x8;

__device__ __forceinline__ float sigm_(float x) { return 1.0f / (1.0f + __expf(-x)); }

__device__ __forceinline__ unsigned short f2bf(float f) {
  union { float f; unsigned int u; } v; v.f = f;
  unsigned int r = v.u + 0x7fffu + ((v.u >> 16) & 1u);  // RNE
  return (unsigned short)(r >> 16);
}

__device__ __forceinline__ void gload_lds16(const void* g, void* l) {
  __builtin_amdgcn_global_load_lds(
      (const __attribute__((address_space(1))) void*)g,
      (__attribute__((address_space(3))) void*)l, 16, 0, 0);
}

// ============================ LayerNorm (fp32 in, bf16 or fp32 out) ============================
template<bool MASKOUT, bool OUTBF>
__global__ __launch_bounds__(256) void ln_kernel(
    const float* __restrict__ in, const float* __restrict__ gw,
    const float* __restrict__ bw, const unsigned char* __restrict__ mask,
    void* __restrict__ outv) {
  int row = blockIdx.x * 4 + (threadIdx.x >> 6);
  int lane = threadIdx.x & 63;
  const float4* x4 = reinterpret_cast<const float4*>(in + (size_t)row * cD);
  float4 v0 = x4[2 * lane];
  float4 v1 = x4[2 * lane + 1];
  float s = v0.x + v0.y + v0.z + v0.w + v1.x + v1.y + v1.z + v1.w;
  float q = v0.x * v0.x + v0.y * v0.y + v0.z * v0.z + v0.w * v0.w +
            v1.x * v1.x + v1.y * v1.y + v1.z * v1.z + v1.w * v1.w;
#pragma unroll
  for (int m = 1; m < 64; m <<= 1) {
    s += __shfl_xor(s, m);
    q += __shfl_xor(q, m);
  }
  float mean = s * (1.0f / cD);
  float var = q * (1.0f / cD) - mean * mean;
  float rs = rsqrtf(var + cEPS);
  float keep = 1.0f;
  if (MASKOUT) keep = mask[row] ? 0.0f : 1.0f;
  const float4* g4 = reinterpret_cast<const float4*>(gw);
  const float4* b4 = reinterpret_cast<const float4*>(bw);
  float4 ga = g4[2 * lane], gb = g4[2 * lane + 1];
  float4 ba = b4[2 * lane], bb = b4[2 * lane + 1];
  float o[8];
  o[0] = ((v0.x - mean) * rs * ga.x + ba.x) * keep;
  o[1] = ((v0.y - mean) * rs * ga.y + ba.y) * keep;
  o[2] = ((v0.z - mean) * rs * ga.z + ba.z) * keep;
  o[3] = ((v0.w - mean) * rs * ga.w + ba.w) * keep;
  o[4] = ((v1.x - mean) * rs * gb.x + bb.x) * keep;
  o[5] = ((v1.y - mean) * rs * gb.y + bb.y) * keep;
  o[6] = ((v1.z - mean) * rs * gb.z + bb.z) * keep;
  o[7] = ((v1.w - mean) * rs * gb.w + bb.w) * keep;
  if (OUTBF) {
    u16x8 p;
#pragma unroll
    for (int i = 0; i < 8; ++i) p[i] = f2bf(o[i]);
    *reinterpret_cast<u16x8*>((unsigned short*)outv + (size_t)row * cD + lane * 8) = p;
  } else {
    float4 o0 = {o[0], o[1], o[2], o[3]}, o1 = {o[4], o[5], o[6], o[7]};
    float4* o4 = reinterpret_cast<float4*>((float*)outv + (size_t)row * cD);
    o4[2 * lane] = o0;
    o4[2 * lane + 1] = o1;
  }
}

// ============================ weight fp32[K,N] -> bf16 W^T[N,K] ============================
__global__ __launch_bounds__(256) void wconv_kernel(
    const float* __restrict__ W, unsigned short* __restrict__ WT, int K, int N) {
  __shared__ float t[64][65];
  const int n0 = blockIdx.x * 64, k0 = blockIdx.y * 64;
  const int tx = threadIdx.x & 63, ty = threadIdx.x >> 6;
#pragma unroll
  for (int i = 0; i < 16; ++i) {
    int kr = ty * 16 + i;
    t[kr][tx] = W[(size_t)(k0 + kr) * N + n0 + tx];
  }
  __syncthreads();
#pragma unroll
  for (int i = 0; i < 16; ++i) {
    int nr = ty * 16 + i;
    WT[(size_t)(n0 + nr) * K + k0 + tx] = f2bf(t[tx][nr]);
  }
}

// ============================ rel_pos fp32 [128][8][64] -> bf16 relT [8][128][64] ============================
__global__ __launch_bounds__(256) void relconv_kernel(
    const float* __restrict__ rel, unsigned short* __restrict__ relT) {
  int flat = (blockIdx.x * 256 + threadIdx.x) * 4;  // 65536 elems total
  int h = flat >> 13, rem = flat & 8191;
  int p = rem >> 6, d = rem & 63;
  float4 v = *reinterpret_cast<const float4*>(rel + ((size_t)p * cNH + h) * cHD + d);
  ushort4 o = {f2bf(v.x), f2bf(v.y), f2bf(v.z), f2bf(v.w)};
  *reinterpret_cast<ushort4*>(relT + flat) = o;
}

// ============================ bf16 MFMA GEMM (m97 structure, linear LDS) ============================
// C[M,N] = act(A[M,K]bf16 @ W[K,N] + bias) [+res] [*mask]; W given as WT[N,K]bf16.
// 128x128 tile, BK=32, 4 waves (2x2 of 64x64), mfma_f32_16x16x32_bf16.
template<bool BIAS, bool SILU, int RES, bool MASK, bool OUTBF>
__global__ __launch_bounds__(256) void mgemm_kernel(
    const unsigned short* __restrict__ A, const unsigned short* __restrict__ WT,
    const float* __restrict__ bias, const float* __restrict__ res,
    const unsigned char* __restrict__ mask, void* __restrict__ outv,
    int N, int K) {
  __shared__ unsigned short ldsA[4096];  // 128 x 32 bf16 = 8 KB
  __shared__ unsigned short ldsB[4096];
  const int tid = threadIdx.x, lane = tid & 63, wid = tid >> 6;
  const int m0 = blockIdx.y * 128, n0 = blockIdx.x * 128;
  const int wr = wid >> 1, wc = wid & 1;  // wave's 64x64 quadrant

  const int sr = wid * 32 + (lane >> 2);
  const int sc = (lane & 3) * 8;  // element offset within k-window (8 bf16 = 16B)
  const unsigned short* a0 = A + (size_t)(m0 + sr) * K + sc;
  const unsigned short* a1 = A + (size_t)(m0 + sr + 16) * K + sc;
  const unsigned short* b0 = WT + (size_t)(n0 + sr) * K + sc;
  const unsigned short* b1 = WT + (size_t)(n0 + sr + 16) * K + sc;
  unsigned short* lA0 = ldsA + wid * 1024;  // row wid*32
  unsigned short* lA1 = lA0 + 512;          // row wid*32+16
  unsigned short* lB0 = ldsB + wid * 1024;
  unsigned short* lB1 = lB0 + 512;

  f32x4 acc[4][4] = {};

  const int fr = lane & 15, fq = lane >> 4;  // fragment row, k-chunk
  const int fco = fq * 8;                    // element col within 32-wide LDS row

  for (int k0 = 0; k0 < K; k0 += 32) {
    __syncthreads();
    gload_lds16(a0 + k0, lA0);
    gload_lds16(a1 + k0, lA1);
    gload_lds16(b0 + k0, lB0);
    gload_lds16(b1 + k0, lB1);
    asm volatile("s_waitcnt vmcnt(0)" ::: "memory");
    __syncthreads();
    bf16x8 af[4], bfr[4];
#pragma unroll
    for (int f = 0; f < 4; ++f) {
      af[f] = *reinterpret_cast<const bf16x8*>(ldsA + (wr * 64 + f * 16 + fr) * 32 + fco);
      bfr[f] = *reinterpret_cast<const bf16x8*>(ldsB + (wc * 64 + f * 16 + fr) * 32 + fco);
    }
#pragma unroll
    for (int i = 0; i < 4; ++i)
#pragma unroll
      for (int j = 0; j < 4; ++j)
        acc[i][j] = __builtin_amdgcn_mfma_f32_16x16x32_bf16(af[i], bfr[j], acc[i][j], 0, 0, 0);
  }

#pragma unroll
  for (int fm = 0; fm < 4; ++fm) {
#pragma unroll
    for (int fn = 0; fn < 4; ++fn) {
      const int cn = n0 + wc * 64 + fn * 16 + fr;
      const float bv = BIAS ? bias[cn] : 0.0f;
#pragma unroll
      for (int j = 0; j < 4; ++j) {
        const int m = m0 + wr * 64 + fm * 16 + fq * 4 + j;
        float t = acc[fm][fn][j] + bv;
        if (SILU) t = t * sigm_(t);
        if (RES == 1) t = res[(size_t)m * N + cn] + t;
        if (RES == 2) t = res[(size_t)m * N + cn] + 0.5f * t;
        if (MASK) t = mask[m] ? 0.0f : t;
        if (OUTBF) ((unsigned short*)outv)[(size_t)m * N + cn] = f2bf(t);
        else       ((float*)outv)[(size_t)m * N + cn] = t;
      }
    }
  }
}

// ============================ banded MFMA attention (bf16 qkv in, bf16 out) ============================
// Block = (b, h, 32 queries) = 2 waves x 16-q tiles; 128 threads.
// Key slots 0..159 = t in [q0-127, q0+32); wave w valid window: pidx = q - t in [0,127].
// QK^T and Q.relT via mfma_16x16x32; rel gathered per (q,slot) from wave-private QR LDS;
// softmax via 16-lane shfl; PV via P(bf16, LDS) x V^T(bf16, LDS).
__global__ __launch_bounds__(128) void attn_kernel(
    const unsigned short* __restrict__ qkv, const unsigned short* __restrict__ relT,
    const unsigned char* __restrict__ mask, unsigned short* __restrict__ out) {
  __shared__ alignas(16) unsigned short Kb[160 * 72];   // [slot][72] (64 d + pad8)
  __shared__ alignas(16) unsigned short VTs[64 * 160];  // [d][slot]
  __shared__ alignas(16) char uni[2][8448];             // per-wave: QR f32[16][132] / P bf16[16][168]
  __shared__ unsigned char msk[160];
  const int tid = threadIdx.x;
  const int b = blockIdx.z, h = blockIdx.y, q0 = blockIdx.x * 32;

  for (int s = tid; s < 160; s += 128) {
    int t = q0 - 127 + s;
    msk[s] = (t < 0 || t >= cT) ? 1 : mask[(size_t)b * cT + t];
  }
  for (int i = tid; i < 1280; i += 128) {  // K: 160 rows x 8 chunks
    int row = i >> 3, ch = i & 7;
    int t = q0 - 127 + row;
    bf16x8 v = {};
    if (t >= 0 && t < cT)
      v = *reinterpret_cast<const bf16x8*>(qkv + (size_t)(b * cT + t) * 1536 + 512 + h * 64 + ch * 8);
    *reinterpret_cast<bf16x8*>(Kb + row * 72 + ch * 8) = v;
  }
  for (int i = tid; i < 1280; i += 128) {  // V -> VT (scalar transpose writes)
    int row = i >> 3, ch = i & 7;
    int t = q0 - 127 + row;
    u16x8 v = {};
    if (t >= 0 && t < cT)
      v = *reinterpret_cast<const u16x8*>(qkv + (size_t)(b * cT + t) * 1536 + 1024 + h * 64 + ch * 8);
#pragma unroll
    for (int e = 0; e < 8; ++e) VTs[(ch * 8 + e) * 160 + row] = v[e];
  }
  __syncthreads();

  const int w = tid >> 6, lane = tid & 63;
  const int fr = lane & 15, fq = lane >> 4;

  // Q A-frags in registers (row = lane&15, k-chunk = (lane>>4)*8)
  const unsigned short* qp = qkv + (size_t)(b * cT + q0 + w * 16 + fr) * 1536 + h * 64;
  bf16x8 qf0 = *reinterpret_cast<const bf16x8*>(qp + fq * 8);
  bf16x8 qf1 = *reinterpret_cast<const bf16x8*>(qp + 32 + fq * 8);

  // S = Q.K^T : 10 key-frags x (K=64 -> 2 mfma)
  f32x4 sacc[10] = {};
#pragma unroll
  for (int f = 0; f < 10; ++f) {
    const unsigned short* kb = Kb + (f * 16 + fr) * 72;
    sacc[f] = __builtin_amdgcn_mfma_f32_16x16x32_bf16(qf0, *reinterpret_cast<const bf16x8*>(kb + fq * 8), sacc[f], 0, 0, 0);
    sacc[f] = __builtin_amdgcn_mfma_f32_16x16x32_bf16(qf1, *reinterpret_cast<const bf16x8*>(kb + 32 + fq * 8), sacc[f], 0, 0, 0);
  }
  // QR = Q.rel^T : 8 p-frags x 2 (B-frags straight from global relT, L2-resident)
  f32x4 qr[8] = {};
  const unsigned short* rT = relT + (size_t)h * 8192;
#pragma unroll
  for (int fp = 0; fp < 8; ++fp) {
    const unsigned short* rb = rT + (fp * 16 + fr) * 64;
    qr[fp] = __builtin_amdgcn_mfma_f32_16x16x32_bf16(qf0, *reinterpret_cast<const bf16x8*>(rb + fq * 8), qr[fp], 0, 0, 0);
    qr[fp] = __builtin_amdgcn_mfma_f32_16x16x32_bf16(qf1, *reinterpret_cast<const bf16x8*>(rb + 32 + fq * 8), qr[fp], 0, 0, 0);
  }
  // dump QR to wave-private LDS [16 q][132 p] f32
  float* QR = reinterpret_cast<float*>(uni[w]);
#pragma unroll
  for (int fp = 0; fp < 8; ++fp)
#pragma unroll
    for (int j = 0; j < 4; ++j)
      QR[(fq * 4 + j) * 132 + fp * 16 + fr] = qr[fp][j];
  asm volatile("s_waitcnt lgkmcnt(0)" ::: "memory");
  __builtin_amdgcn_sched_barrier(0);

  // assemble scores + gather rel + mask; softmax over 160 slots per q-row
  float pmat[10][4];
  float mrow[4] = {-3e38f, -3e38f, -3e38f, -3e38f};
#pragma unroll
  for (int f = 0; f < 10; ++f) {
    int slot = f * 16 + fr;
#pragma unroll
    for (int j = 0; j < 4; ++j) {
      int row = fq * 4 + j;
      int pidx = w * 16 + row + 127 - slot;  // q - t
      float v = -1e30f;
      if ((unsigned)pidx <= 127u && !msk[slot])
        v = (sacc[f][j] + QR[row * 132 + pidx]) * 0.125f;
      pmat[f][j] = v;
      mrow[j] = fmaxf(mrow[j], v);
    }
  }
#pragma unroll
  for (int j = 0; j < 4; ++j) {
    float m = mrow[j];
    m = fmaxf(m, __shfl_xor(m, 1));
    m = fmaxf(m, __shfl_xor(m, 2));
    m = fmaxf(m, __shfl_xor(m, 4));
    m = fmaxf(m, __shfl_xor(m, 8));
    mrow[j] = m;
  }
  float srow[4] = {0.f, 0.f, 0.f, 0.f};
#pragma unroll
  for (int f = 0; f < 10; ++f)
#pragma unroll
    for (int j = 0; j < 4; ++j) {
      float p = __expf(pmat[f][j] - mrow[j]);
      pmat[f][j] = p;
      srow[j] += p;
    }
#pragma unroll
  for (int j = 0; j < 4; ++j) {
    float s = srow[j];
    s += __shfl_xor(s, 1);
    s += __shfl_xor(s, 2);
    s += __shfl_xor(s, 4);
    s += __shfl_xor(s, 8);
    srow[j] = 1.0f / s;
  }
  // P -> bf16 LDS [16 q][168 slots] (aliases QR region; all QR reads are done)
  unsigned short* P = reinterpret_cast<unsigned short*>(uni[w]);
#pragma unroll
  for (int f = 0; f < 10; ++f)
#pragma unroll
    for (int j = 0; j < 4; ++j)
      P[(fq * 4 + j) * 168 + f * 16 + fr] = f2bf(pmat[f][j] * srow[j]);
  asm volatile("s_waitcnt lgkmcnt(0)" ::: "memory");
  __builtin_amdgcn_sched_barrier(0);

  // PV: A = P [q][slot], B = VT [d][slot]; K = 160 -> 5 k-steps
  f32x4 oacc[4] = {};
#pragma unroll
  for (int ks = 0; ks < 5; ++ks) {
    bf16x8 pa = *reinterpret_cast<const bf16x8*>(P + fr * 168 + ks * 32 + fq * 8);
#pragma unroll
    for (int fn = 0; fn < 4; ++fn)
      oacc[fn] = __builtin_amdgcn_mfma_f32_16x16x32_bf16(
          pa, *reinterpret_cast<const bf16x8*>(VTs + (fn * 16 + fr) * 160 + ks * 32 + fq * 8), oacc[fn], 0, 0, 0);
  }
#pragma unroll
  for (int fn = 0; fn < 4; ++fn)
#pragma unroll
    for (int j = 0; j < 4; ++j)
      out[(size_t)(b * cT + q0 + w * 16 + fq * 4 + j) * cD + h * 64 + fn * 16 + fr] = f2bf(oacc[fn][j]);
}

// ============================ GLU + depthwise conv + BN + SiLU (fp32 in, bf16 out) ============================
__global__ __launch_bounds__(256) void dwconv_kernel(
    const float* __restrict__ pw1out, const float* __restrict__ dww,
    const float* __restrict__ dwb, const float* __restrict__ bng,
    const float* __restrict__ bnb, const float* __restrict__ bnm,
    const float* __restrict__ bnv, unsigned short* __restrict__ out) {
  constexpr int TT = 64, DD = 128, PAD = cK - 1;
  __shared__ alignas(16) float g_lds[TT + PAD][DD];
  const int b = blockIdx.z, d0 = blockIdx.y * DD, t0 = blockIdx.x * TT;
  const int tid = threadIdx.x;

  for (int f = tid; f < (TT + PAD) * (DD / 4); f += 256) {
    int row = f >> 5, c4 = (f & 31) * 4;
    int t = t0 - PAD + row;
    float4 val = {0.f, 0.f, 0.f, 0.f};
    if (t >= 0) {
      const float* base = pw1out + (size_t)(b * cT + t) * (2 * cD) + d0 + c4;
      float4 a = *reinterpret_cast<const float4*>(base);
      float4 g = *reinterpret_cast<const float4*>(base + cD);
      val.x = a.x * sigm_(g.x);
      val.y = a.y * sigm_(g.y);
      val.z = a.z * sigm_(g.z);
      val.w = a.w * sigm_(g.w);
    }
    *reinterpret_cast<float4*>(&g_lds[row][c4]) = val;
  }
  __syncthreads();

  const int dl = tid & 127, tg = tid >> 7;
  const int d = d0 + dl;
  float w[cK];
  const float4* w4 = reinterpret_cast<const float4*>(dww + (size_t)d * cK);
#pragma unroll
  for (int i = 0; i < cK / 4; ++i) {
    float4 t4 = w4[i];
    w[i * 4 + 0] = t4.x; w[i * 4 + 1] = t4.y; w[i * 4 + 2] = t4.z; w[i * 4 + 3] = t4.w;
  }
  const float bias = dwb[d];
  const float scale = bng[d] * rsqrtf(bnv[d] + cEPS);
  const float shift = bnb[d] - bnm[d] * scale;
#pragma unroll 4
  for (int i = 0; i < 32; ++i) {
    int tl = tg * 32 + i;
    float acc = bias;
#pragma unroll
    for (int k = 0; k < cK; ++k) acc += w[k] * g_lds[tl + k][dl];
    float v = acc * scale + shift;
    v = v * sigm_(v);
    out[(size_t)(b * cT + t0 + tl) * cD + d] = f2bf(v);
  }
}

// ============================ launch ============================
extern "C" void kernel_launch(void* const* d_in, const int* in_sizes, int n_in,
                              void* d_out, int out_size, void* d_ws, size_t ws_size,
                              hipStream_t stream) {
  const float* x = (const float*)d_in[0];
  const unsigned char* mask = (const unsigned char*)d_in[1];
  const float* ff1_ng = (const float*)d_in[2];
  const float* ff1_nb = (const float*)d_in[3];
  const float* ff1_w1 = (const float*)d_in[4];
  const float* ff1_b1 = (const float*)d_in[5];
  const float* ff1_w2 = (const float*)d_in[6];
  const float* ff1_b2 = (const float*)d_in[7];
  const float* mha_ng = (const float*)d_in[8];
  const float* mha_nb = (const float*)d_in[9];
  const float* wqkv = (const float*)d_in[10];
  const float* wout = (const float*)d_in[11];
  const float* bout = (const float*)d_in[12];
  const float* rel_pos = (const float*)d_in[13];
  const float* conv_ng = (const float*)d_in[14];
  const float* conv_nb = (const float*)d_in[15];
  const float* pw1_w = (const float*)d_in[16];
  const float* pw1_b = (const float*)d_in[17];
  const float* dw_w = (const float*)d_in[18];
  const float* dw_b = (const float*)d_in[19];
  const float* bn_g = (const float*)d_in[20];
  const float* bn_b = (const float*)d_in[21];
  const float* bn_m = (const float*)d_in[22];
  const float* bn_v = (const float*)d_in[23];
  const float* pw2_w = (const float*)d_in[24];
  const float* pw2_b = (const float*)d_in[25];
  const float* ff2_ng = (const float*)d_in[26];
  const float* ff2_nb = (const float*)d_in[27];
  const float* ff2_w1 = (const float*)d_in[28];
  const float* ff2_b1 = (const float*)d_in[29];
  const float* ff2_w2 = (const float*)d_in[30];
  const float* ff2_b2 = (const float*)d_in[31];
  const float* final_ng = (const float*)d_in[32];
  const float* final_nb = (const float*)d_in[33];

  float* X = (float*)d_out;  // fp32 residual stream
  char* wsb = (char*)d_ws;
  unsigned short* lnb = (unsigned short*)wsb;                  // [8192,512] bf16, 8 MB
  unsigned short* auxb = (unsigned short*)(wsb + (8 << 20));   // [8192,512] bf16, 8 MB
  char* big = wsb + (16 << 20);                                // qkv bf16 (24 MB) / ffn-mid bf16 / pw1out f32
  unsigned short* wT = (unsigned short*)(wsb + (64 << 20));    // transposed bf16 weights + relT
  float* bigf = (float*)big;
  unsigned short* bigh = (unsigned short*)big;

  unsigned short* wt_ff1w1 = wT + 0;        // [2048,512]
  unsigned short* wt_ff1w2 = wT + 1048576;  // [512,2048]
  unsigned short* wt_qkv   = wT + 2097152;  // [1536,512]
  unsigned short* wt_out   = wT + 2883584;  // [512,512]
  unsigned short* wt_pw1   = wT + 3145728;  // [1024,512]
  unsigned short* wt_pw2   = wT + 3670016;  // [512,512]
  unsigned short* wt_ff2w1 = wT + 3932160;  // [2048,512]
  unsigned short* wt_ff2w2 = wT + 4980736;  // [512,2048]
  unsigned short* relT     = wT + 6029312;  // [8][128][64] bf16

  const dim3 blk(256);
  const dim3 ln_grid(cM / 4);

  // ---- weight prep ----
  wconv_kernel<<<dim3(2048 / 64, 512 / 64), blk, 0, stream>>>(ff1_w1, wt_ff1w1, 512, 2048);
  wconv_kernel<<<dim3(512 / 64, 2048 / 64), blk, 0, stream>>>(ff1_w2, wt_ff1w2, 2048, 512);
  wconv_kernel<<<dim3(1536 / 64, 512 / 64), blk, 0, stream>>>(wqkv, wt_qkv, 512, 1536);
  wconv_kernel<<<dim3(512 / 64, 512 / 64), blk, 0, stream>>>(wout, wt_out, 512, 512);
  wconv_kernel<<<dim3(1024 / 64, 512 / 64), blk, 0, stream>>>(pw1_w, wt_pw1, 512, 1024);
  wconv_kernel<<<dim3(512 / 64, 512 / 64), blk, 0, stream>>>(pw2_w, wt_pw2, 512, 512);
  wconv_kernel<<<dim3(2048 / 64, 512 / 64), blk, 0, stream>>>(ff2_w1, wt_ff2w1, 512, 2048);
  wconv_kernel<<<dim3(512 / 64, 2048 / 64), blk, 0, stream>>>(ff2_w2, wt_ff2w2, 2048, 512);
  relconv_kernel<<<dim3(64), blk, 0, stream>>>(rel_pos, relT);

  // ---- FFN1 ----
  ln_kernel<false, true><<<ln_grid, blk, 0, stream>>>(x, ff1_ng, ff1_nb, nullptr, lnb);
  mgemm_kernel<true, true, 0, false, true><<<dim3(16, 64), blk, 0, stream>>>(
      lnb, wt_ff1w1, ff1_b1, nullptr, nullptr, bigh, 2048, 512);
  mgemm_kernel<true, false, 2, true, false><<<dim3(4, 64), blk, 0, stream>>>(
      bigh, wt_ff1w2, ff1_b2, x, mask, X, 512, 2048);
  // ---- MHA ----
  ln_kernel<false, true><<<ln_grid, blk, 0, stream>>>(X, mha_ng, mha_nb, nullptr, lnb);
  mgemm_kernel<false, false, 0, false, true><<<dim3(12, 64), blk, 0, stream>>>(
      lnb, wt_qkv, nullptr, nullptr, nullptr, bigh, 1536, 512);
  attn_kernel<<<dim3(cT / 32, cNH, cB), dim3(128), 0, stream>>>(bigh, relT, mask, auxb);
  mgemm_kernel<true, false, 1, true, false><<<dim3(4, 64), blk, 0, stream>>>(
      auxb, wt_out, bout, X, mask, X, 512, 512);
  // ---- Conv module ----
  ln_kernel<false, true><<<ln_grid, blk, 0, stream>>>(X, conv_ng, conv_nb, nullptr, lnb);
  mgemm_kernel<true, false, 0, false, false><<<dim3(8, 64), blk, 0, stream>>>(
      lnb, wt_pw1, pw1_b, nullptr, nullptr, bigf, 1024, 512);
  dwconv_kernel<<<dim3(cT / 64, cD / 128, cB), blk, 0, stream>>>(
      bigf, dw_w, dw_b, bn_g, bn_b, bn_m, bn_v, auxb);
  mgemm_kernel<true, false, 1, true, false><<<dim3(4, 64), blk, 0, stream>>>(
      auxb, wt_pw2, pw2_b, X, mask, X, 512, 512);
  // ---- FFN2 ----
  ln_kernel<false, true><<<ln_grid, blk, 0, stream>>>(X, ff2_ng, ff2_nb, nullptr, lnb);
  mgemm_kernel<true, true, 0, false, true><<<dim3(16, 64), blk, 0, stream>>>(
      lnb, wt_ff2w1, ff2_b1, nullptr, nullptr, bigh, 2048, 512);
  mgemm_kernel<true, false, 2, true, false><<<dim3(4, 64), blk, 0, stream>>>(
      bigh, wt_ff2w2, ff2_b2, X, mask, X, 512, 2048);
  // ---- final LN + mask (fp32 out, in-place) ----
  ln_kernel<true, false><<<ln_grid, blk, 0, stream>>>(X, final_ng, final_nb, mask, X);
}

// Round 9
// 451.359 us; speedup vs baseline: 4.1231x; 1.1540x over previous
//
#include <hip/hip_runtime.h>

// ============================ problem constants ============================
constexpr int cB = 8, cT = 1024, cD = 512, cNH = 8, cHD = 64, cH = 127, cK = 32;
constexpr int cM = cB * cT;  // 8192 token rows
constexpr float cEPS = 1e-5f;

typedef __attribute__((ext_vector_type(8))) short bf16x8;
typedef __attribute__((ext_vector_type(4))) float f32x4;
typedef __attribute__((ext_vector_type(8))) unsigned short u16x8;

__device__ __forceinline__ float sigm_(float x) { return 1.0f / (1.0f + __expf(-x)); }

__device__ __forceinline__ unsigned short f2bf(float f) {
  union { float f; unsigned int u; } v; v.f = f;
  unsigned int r = v.u + 0x7fffu + ((v.u >> 16) & 1u);  // RNE
  return (unsigned short)(r >> 16);
}
__device__ __forceinline__ float bf2f(unsigned short u) {
  union { unsigned int u; float f; } v; v.u = (unsigned int)u << 16;
  return v.f;
}

__device__ __forceinline__ void gload_lds16(const void* g, void* l) {
  __builtin_amdgcn_global_load_lds(
      (const __attribute__((address_space(1))) void*)g,
      (__attribute__((address_space(3))) void*)l, 16, 0, 0);
}

// ============================ LayerNorm (fp32 in, bf16 or fp32 out) ============================
template<bool MASKOUT, bool OUTBF>
__global__ __launch_bounds__(256) void ln_kernel(
    const float* __restrict__ in, const float* __restrict__ gw,
    const float* __restrict__ bw, const unsigned char* __restrict__ mask,
    void* __restrict__ outv) {
  int row = blockIdx.x * 4 + (threadIdx.x >> 6);
  int lane = threadIdx.x & 63;
  const float4* x4 = reinterpret_cast<const float4*>(in + (size_t)row * cD);
  float4 v0 = x4[2 * lane];
  float4 v1 = x4[2 * lane + 1];
  float s = v0.x + v0.y + v0.z + v0.w + v1.x + v1.y + v1.z + v1.w;
  float q = v0.x * v0.x + v0.y * v0.y + v0.z * v0.z + v0.w * v0.w +
            v1.x * v1.x + v1.y * v1.y + v1.z * v1.z + v1.w * v1.w;
#pragma unroll
  for (int m = 1; m < 64; m <<= 1) {
    s += __shfl_xor(s, m);
    q += __shfl_xor(q, m);
  }
  float mean = s * (1.0f / cD);
  float var = q * (1.0f / cD) - mean * mean;
  float rs = rsqrtf(var + cEPS);
  float keep = 1.0f;
  if (MASKOUT) keep = mask[row] ? 0.0f : 1.0f;
  const float4* g4 = reinterpret_cast<const float4*>(gw);
  const float4* b4 = reinterpret_cast<const float4*>(bw);
  float4 ga = g4[2 * lane], gb = g4[2 * lane + 1];
  float4 ba = b4[2 * lane], bb = b4[2 * lane + 1];
  float o[8];
  o[0] = ((v0.x - mean) * rs * ga.x + ba.x) * keep;
  o[1] = ((v0.y - mean) * rs * ga.y + ba.y) * keep;
  o[2] = ((v0.z - mean) * rs * ga.z + ba.z) * keep;
  o[3] = ((v0.w - mean) * rs * ga.w + ba.w) * keep;
  o[4] = ((v1.x - mean) * rs * gb.x + bb.x) * keep;
  o[5] = ((v1.y - mean) * rs * gb.y + bb.y) * keep;
  o[6] = ((v1.z - mean) * rs * gb.z + bb.z) * keep;
  o[7] = ((v1.w - mean) * rs * gb.w + bb.w) * keep;
  if (OUTBF) {
    u16x8 p;
#pragma unroll
    for (int i = 0; i < 8; ++i) p[i] = f2bf(o[i]);
    *reinterpret_cast<u16x8*>((unsigned short*)outv + (size_t)row * cD + lane * 8) = p;
  } else {
    float4 o0 = {o[0], o[1], o[2], o[3]}, o1 = {o[4], o[5], o[6], o[7]};
    float4* o4 = reinterpret_cast<float4*>((float*)outv + (size_t)row * cD);
    o4[2 * lane] = o0;
    o4[2 * lane + 1] = o1;
  }
}

// ============================ weight fp32[K,N] -> bf16 W^T[N,K] ============================
__global__ __launch_bounds__(256) void wconv_kernel(
    const float* __restrict__ W, unsigned short* __restrict__ WT, int K, int N) {
  __shared__ float t[64][65];
  const int n0 = blockIdx.x * 64, k0 = blockIdx.y * 64;
  const int tx = threadIdx.x & 63, ty = threadIdx.x >> 6;
#pragma unroll
  for (int i = 0; i < 16; ++i) {
    int kr = ty * 16 + i;
    t[kr][tx] = W[(size_t)(k0 + kr) * N + n0 + tx];
  }
  __syncthreads();
#pragma unroll
  for (int i = 0; i < 16; ++i) {
    int nr = ty * 16 + i;
    WT[(size_t)(n0 + nr) * K + k0 + tx] = f2bf(t[tx][nr]);
  }
}

// ============================ rel_pos fp32 [128][8][64] -> bf16 relT [8][128][64] ============================
__global__ __launch_bounds__(256) void relconv_kernel(
    const float* __restrict__ rel, unsigned short* __restrict__ relT) {
  int flat = (blockIdx.x * 256 + threadIdx.x) * 4;  // 65536 elems total
  int h = flat >> 13, rem = flat & 8191;
  int p = rem >> 6, d = rem & 63;
  float4 v = *reinterpret_cast<const float4*>(rel + ((size_t)p * cNH + h) * cHD + d);
  ushort4 o = {f2bf(v.x), f2bf(v.y), f2bf(v.z), f2bf(v.w)};
  *reinterpret_cast<ushort4*>(relT + flat) = o;
}

// ============================ bf16 MFMA GEMM (2-phase double-buffered) ============================
// C[M,N] = act(A[M,K]bf16 @ W[K,N] + bias) [+res] [*mask]; W given as WT[N,K]bf16.
// 128x128 tile, BK=32, 4 waves (2x2 of 64x64). 2-phase pipeline: issue next-tile
// global_load_lds BEFORE ds_read+MFMA of current tile; one vmcnt(0)+barrier per step.
template<bool BIAS, bool SILU, int RES, bool MASK, bool OUTBF>
__global__ __launch_bounds__(256) void mgemm_kernel(
    const unsigned short* __restrict__ A, const unsigned short* __restrict__ WT,
    const float* __restrict__ bias, const float* __restrict__ res,
    const unsigned char* __restrict__ mask, void* __restrict__ outv,
    int N, int K) {
  __shared__ unsigned short ldsA[2][4096];  // 2 x 128x32 bf16
  __shared__ unsigned short ldsB[2][4096];
  const int tid = threadIdx.x, lane = tid & 63, wid = tid >> 6;
  const int m0 = blockIdx.y * 128, n0 = blockIdx.x * 128;
  const int wr = wid >> 1, wc = wid & 1;  // wave's 64x64 quadrant

  const int sr = wid * 32 + (lane >> 2);
  const int sc = (lane & 3) * 8;  // element offset within k-window (8 bf16 = 16B)
  const unsigned short* a0 = A + (size_t)(m0 + sr) * K + sc;
  const unsigned short* a1 = A + (size_t)(m0 + sr + 16) * K + sc;
  const unsigned short* b0 = WT + (size_t)(n0 + sr) * K + sc;
  const unsigned short* b1 = WT + (size_t)(n0 + sr + 16) * K + sc;
  const int wof = wid * 1024;  // LDS base (shorts) for this wave's 32 rows

  f32x4 acc[4][4] = {};

  const int fr = lane & 15, fq = lane >> 4;  // fragment row, k-chunk
  const int fco = fq * 8;

  const int nt = K >> 5;
  // prologue: stage tile 0 into buffer 0
  gload_lds16(a0, &ldsA[0][wof]);
  gload_lds16(a1, &ldsA[0][wof + 512]);
  gload_lds16(b0, &ldsB[0][wof]);
  gload_lds16(b1, &ldsB[0][wof + 512]);
  asm volatile("s_waitcnt vmcnt(0)" ::: "memory");
  __syncthreads();

  int cur = 0;
  for (int t = 0; t < nt; ++t) {
    if (t + 1 < nt) {  // issue next-tile staging first; latency hides under MFMA
      const int k1 = (t + 1) << 5;
      gload_lds16(a0 + k1, &ldsA[cur ^ 1][wof]);
      gload_lds16(a1 + k1, &ldsA[cur ^ 1][wof + 512]);
      gload_lds16(b0 + k1, &ldsB[cur ^ 1][wof]);
      gload_lds16(b1 + k1, &ldsB[cur ^ 1][wof + 512]);
    }
    bf16x8 af[4], bfr[4];
#pragma unroll
    for (int f = 0; f < 4; ++f) {
      af[f] = *reinterpret_cast<const bf16x8*>(&ldsA[cur][(wr * 64 + f * 16 + fr) * 32 + fco]);
      bfr[f] = *reinterpret_cast<const bf16x8*>(&ldsB[cur][(wc * 64 + f * 16 + fr) * 32 + fco]);
    }
#pragma unroll
    for (int i = 0; i < 4; ++i)
#pragma unroll
      for (int j = 0; j < 4; ++j)
        acc[i][j] = __builtin_amdgcn_mfma_f32_16x16x32_bf16(af[i], bfr[j], acc[i][j], 0, 0, 0);
    asm volatile("s_waitcnt vmcnt(0)" ::: "memory");
    __syncthreads();
    cur ^= 1;
  }

#pragma unroll
  for (int fm = 0; fm < 4; ++fm) {
#pragma unroll
    for (int fn = 0; fn < 4; ++fn) {
      const int cn = n0 + wc * 64 + fn * 16 + fr;
      const float bv = BIAS ? bias[cn] : 0.0f;
#pragma unroll
      for (int j = 0; j < 4; ++j) {
        const int m = m0 + wr * 64 + fm * 16 + fq * 4 + j;
        float t = acc[fm][fn][j] + bv;
        if (SILU) t = t * sigm_(t);
        if (RES == 1) t = res[(size_t)m * N + cn] + t;
        if (RES == 2) t = res[(size_t)m * N + cn] + 0.5f * t;
        if (MASK) t = mask[m] ? 0.0f : t;
        if (OUTBF) ((unsigned short*)outv)[(size_t)m * N + cn] = f2bf(t);
        else       ((float*)outv)[(size_t)m * N + cn] = t;
      }
    }
  }
}

// ============================ banded MFMA attention (bf16 qkv in, bf16 out) ============================
// Block = (b, h, 64 queries) = 4 waves x 16-q tiles; 256 threads.
// Key slots 0..191: t = q0-127+s. K staged in KV [192][72]; after QK, V is staged
// TRANSPOSED into the SAME LDS region as VT [64][200] (stride 200: 100 words = 4 mod 32
// -> uniform bank spread for b128; fixes round-7's 8-way at stride 160).
// QR f32 [16][132] per wave, later aliased by P bf16 [16][200].
__global__ __launch_bounds__(256) void attn_kernel(
    const unsigned short* __restrict__ qkv, const unsigned short* __restrict__ relT,
    const unsigned char* __restrict__ mask, unsigned short* __restrict__ out) {
  __shared__ alignas(16) unsigned short KV[192 * 72];  // K [slot][72]; later VT [64][200]
  __shared__ alignas(16) float QRu[4][16 * 132];       // per-wave QR f32; later P bf16 [16][200]
  __shared__ unsigned char msk[192];
  const int tid = threadIdx.x;
  const int b = blockIdx.z, h = blockIdx.y, q0 = blockIdx.x * 64;

  for (int s = tid; s < 192; s += 256) {
    int t = q0 - 127 + s;
    msk[s] = (t < 0 || t >= cT) ? 1 : mask[(size_t)b * cT + t];
  }
  for (int i = tid; i < 1536; i += 256) {  // K: 192 rows x 8 chunks
    int row = i >> 3, ch = i & 7;
    int t = q0 - 127 + row;
    bf16x8 v = {};
    if (t >= 0 && t < cT)
      v = *reinterpret_cast<const bf16x8*>(qkv + (size_t)(b * cT + t) * 1536 + 512 + h * 64 + ch * 8);
    *reinterpret_cast<bf16x8*>(KV + row * 72 + ch * 8) = v;
  }
  __syncthreads();

  const int w = tid >> 6, lane = tid & 63;
  const int fr = lane & 15, fq = lane >> 4;

  // Q A-frags in registers (q row = q0 + w*16 + fr)
  const unsigned short* qp = qkv + (size_t)(b * cT + q0 + w * 16 + fr) * 1536 + h * 64;
  bf16x8 qf0 = *reinterpret_cast<const bf16x8*>(qp + fq * 8);
  bf16x8 qf1 = *reinterpret_cast<const bf16x8*>(qp + 32 + fq * 8);

  // S = Q.K^T : 12 key-frags x (K=64 -> 2 mfma)
  f32x4 sacc[12] = {};
#pragma unroll
  for (int f = 0; f < 12; ++f) {
    const unsigned short* kb = KV + (f * 16 + fr) * 72;
    sacc[f] = __builtin_amdgcn_mfma_f32_16x16x32_bf16(qf0, *reinterpret_cast<const bf16x8*>(kb + fq * 8), sacc[f], 0, 0, 0);
    sacc[f] = __builtin_amdgcn_mfma_f32_16x16x32_bf16(qf1, *reinterpret_cast<const bf16x8*>(kb + 32 + fq * 8), sacc[f], 0, 0, 0);
  }
  // QR = Q.rel^T : 8 p-frags x 2 (B-frags from global relT, L2-resident)
  f32x4 qr[8] = {};
  const unsigned short* rT = relT + (size_t)h * 8192;
#pragma unroll
  for (int fp = 0; fp < 8; ++fp) {
    const unsigned short* rb = rT + (fp * 16 + fr) * 64;
    qr[fp] = __builtin_amdgcn_mfma_f32_16x16x32_bf16(qf0, *reinterpret_cast<const bf16x8*>(rb + fq * 8), qr[fp], 0, 0, 0);
    qr[fp] = __builtin_amdgcn_mfma_f32_16x16x32_bf16(qf1, *reinterpret_cast<const bf16x8*>(rb + 32 + fq * 8), qr[fp], 0, 0, 0);
  }
  float* QR = QRu[w];
#pragma unroll
  for (int fp = 0; fp < 8; ++fp)
#pragma unroll
    for (int j = 0; j < 4; ++j)
      QR[(fq * 4 + j) * 132 + fp * 16 + fr] = qr[fp][j];
  asm volatile("s_waitcnt lgkmcnt(0)" ::: "memory");
  __builtin_amdgcn_sched_barrier(0);

  // gather rel + band/pad mask; softmax over 192 slots per q-row
  float mrow[4] = {-3e38f, -3e38f, -3e38f, -3e38f};
#pragma unroll
  for (int f = 0; f < 12; ++f) {
    int slot = f * 16 + fr;
#pragma unroll
    for (int j = 0; j < 4; ++j) {
      int row = fq * 4 + j;
      int pidx = w * 16 + row + 127 - slot;  // q - t
      float v = -1e30f;
      if ((unsigned)pidx <= 127u && !msk[slot])
        v = (sacc[f][j] + QR[row * 132 + pidx]) * 0.125f;
      sacc[f][j] = v;
      mrow[j] = fmaxf(mrow[j], v);
    }
  }
#pragma unroll
  for (int j = 0; j < 4; ++j) {
    float m = mrow[j];
    m = fmaxf(m, __shfl_xor(m, 1));
    m = fmaxf(m, __shfl_xor(m, 2));
    m = fmaxf(m, __shfl_xor(m, 4));
    m = fmaxf(m, __shfl_xor(m, 8));
    mrow[j] = m;
  }
  float srow[4] = {0.f, 0.f, 0.f, 0.f};
#pragma unroll
  for (int f = 0; f < 12; ++f)
#pragma unroll
    for (int j = 0; j < 4; ++j) {
      float p = __expf(sacc[f][j] - mrow[j]);
      sacc[f][j] = p;
      srow[j] += p;
    }
#pragma unroll
  for (int j = 0; j < 4; ++j) {
    float s = srow[j];
    s += __shfl_xor(s, 1);
    s += __shfl_xor(s, 2);
    s += __shfl_xor(s, 4);
    s += __shfl_xor(s, 8);
    srow[j] = 1.0f / s;
  }
  // P -> bf16 [16][200], aliases this wave's QR region (all QR reads done above)
  unsigned short* P = reinterpret_cast<unsigned short*>(QRu[w]);
#pragma unroll
  for (int f = 0; f < 12; ++f)
#pragma unroll
    for (int j = 0; j < 4; ++j)
      P[(fq * 4 + j) * 200 + f * 16 + fr] = f2bf(sacc[f][j] * srow[j]);

  // all waves must finish reading K before V overwrites KV
  __syncthreads();
  {
    unsigned short* VT = KV;  // [64 d][200 slots]
    for (int i = tid; i < 1536; i += 256) {
      int row = i >> 3, ch = i & 7;
      int t = q0 - 127 + row;
      u16x8 v = {};
      if (t >= 0 && t < cT)
        v = *reinterpret_cast<const u16x8*>(qkv + (size_t)(b * cT + t) * 1536 + 1024 + h * 64 + ch * 8);
#pragma unroll
      for (int e = 0; e < 8; ++e) VT[(ch * 8 + e) * 200 + row] = v[e];
    }
  }
  __syncthreads();

  // PV: A = P [q][slot], B = VT [d][slot]; K = 192 -> 6 k-steps
  f32x4 oacc[4] = {};
  const unsigned short* VT = KV;
#pragma unroll
  for (int ks = 0; ks < 6; ++ks) {
    bf16x8 pa = *reinterpret_cast<const bf16x8*>(P + fr * 200 + ks * 32 + fq * 8);
#pragma unroll
    for (int fn = 0; fn < 4; ++fn)
      oacc[fn] = __builtin_amdgcn_mfma_f32_16x16x32_bf16(
          pa, *reinterpret_cast<const bf16x8*>(VT + (fn * 16 + fr) * 200 + ks * 32 + fq * 8), oacc[fn], 0, 0, 0);
  }
#pragma unroll
  for (int fn = 0; fn < 4; ++fn)
#pragma unroll
    for (int j = 0; j < 4; ++j)
      out[(size_t)(b * cT + q0 + w * 16 + fq * 4 + j) * cD + h * 64 + fn * 16 + fr] = f2bf(oacc[fn][j]);
}

// ============================ GLU + depthwise conv + BN + SiLU (bf16 in, bf16 out) ============================
__global__ __launch_bounds__(256) void dwconv_kernel(
    const unsigned short* __restrict__ pw1out, const float* __restrict__ dww,
    const float* __restrict__ dwb, const float* __restrict__ bng,
    const float* __restrict__ bnb, const float* __restrict__ bnm,
    const float* __restrict__ bnv, unsigned short* __restrict__ out) {
  constexpr int TT = 64, DD = 128, PAD = cK - 1;
  __shared__ alignas(16) float g_lds[TT + PAD][DD];
  const int b = blockIdx.z, d0 = blockIdx.y * DD, t0 = blockIdx.x * TT;
  const int tid = threadIdx.x;

  for (int f = tid; f < (TT + PAD) * (DD / 4); f += 256) {
    int row = f >> 5, c4 = (f & 31) * 4;
    int t = t0 - PAD + row;
    float4 val = {0.f, 0.f, 0.f, 0.f};
    if (t >= 0) {
      const unsigned short* base = pw1out + (size_t)(b * cT + t) * (2 * cD) + d0 + c4;
      ushort4 a = *reinterpret_cast<const ushort4*>(base);
      ushort4 g = *reinterpret_cast<const ushort4*>(base + cD);
      val.x = bf2f(a.x) * sigm_(bf2f(g.x));
      val.y = bf2f(a.y) * sigm_(bf2f(g.y));
      val.z = bf2f(a.z) * sigm_(bf2f(g.z));
      val.w = bf2f(a.w) * sigm_(bf2f(g.w));
    }
    *reinterpret_cast<float4*>(&g_lds[row][c4]) = val;
  }
  __syncthreads();

  const int dl = tid & 127, tg = tid >> 7;
  const int d = d0 + dl;
  float w[cK];
  const float4* w4 = reinterpret_cast<const float4*>(dww + (size_t)d * cK);
#pragma unroll
  for (int i = 0; i < cK / 4; ++i) {
    float4 t4 = w4[i];
    w[i * 4 + 0] = t4.x; w[i * 4 + 1] = t4.y; w[i * 4 + 2] = t4.z; w[i * 4 + 3] = t4.w;
  }
  const float bias = dwb[d];
  const float scale = bng[d] * rsqrtf(bnv[d] + cEPS);
  const float shift = bnb[d] - bnm[d] * scale;
#pragma unroll 4
  for (int i = 0; i < 32; ++i) {
    int tl = tg * 32 + i;
    float acc = bias;
#pragma unroll
    for (int k = 0; k < cK; ++k) acc += w[k] * g_lds[tl + k][dl];
    float v = acc * scale + shift;
    v = v * sigm_(v);
    out[(size_t)(b * cT + t0 + tl) * cD + d] = f2bf(v);
  }
}

// ============================ launch ============================
extern "C" void kernel_launch(void* const* d_in, const int* in_sizes, int n_in,
                              void* d_out, int out_size, void* d_ws, size_t ws_size,
                              hipStream_t stream) {
  const float* x = (const float*)d_in[0];
  const unsigned char* mask = (const unsigned char*)d_in[1];
  const float* ff1_ng = (const float*)d_in[2];
  const float* ff1_nb = (const float*)d_in[3];
  const float* ff1_w1 = (const float*)d_in[4];
  const float* ff1_b1 = (const float*)d_in[5];
  const float* ff1_w2 = (const float*)d_in[6];
  const float* ff1_b2 = (const float*)d_in[7];
  const float* mha_ng = (const float*)d_in[8];
  const float* mha_nb = (const float*)d_in[9];
  const float* wqkv = (const float*)d_in[10];
  const float* wout = (const float*)d_in[11];
  const float* bout = (const float*)d_in[12];
  const float* rel_pos = (const float*)d_in[13];
  const float* conv_ng = (const float*)d_in[14];
  const float* conv_nb = (const float*)d_in[15];
  const float* pw1_w = (const float*)d_in[16];
  const float* pw1_b = (const float*)d_in[17];
  const float* dw_w = (const float*)d_in[18];
  const float* dw_b = (const float*)d_in[19];
  const float* bn_g = (const float*)d_in[20];
  const float* bn_b = (const float*)d_in[21];
  const float* bn_m = (const float*)d_in[22];
  const float* bn_v = (const float*)d_in[23];
  const float* pw2_w = (const float*)d_in[24];
  const float* pw2_b = (const float*)d_in[25];
  const float* ff2_ng = (const float*)d_in[26];
  const float* ff2_nb = (const float*)d_in[27];
  const float* ff2_w1 = (const float*)d_in[28];
  const float* ff2_b1 = (const float*)d_in[29];
  const float* ff2_w2 = (const float*)d_in[30];
  const float* ff2_b2 = (const float*)d_in[31];
  const float* final_ng = (const float*)d_in[32];
  const float* final_nb = (const float*)d_in[33];

  float* X = (float*)d_out;  // fp32 residual stream
  char* wsb = (char*)d_ws;
  unsigned short* lnb = (unsigned short*)wsb;                  // [8192,512] bf16, 8 MB
  unsigned short* auxb = (unsigned short*)(wsb + (8 << 20));   // [8192,512] bf16, 8 MB
  char* big = wsb + (16 << 20);                                // qkv bf16 / ffn-mid bf16 / pw1out bf16
  unsigned short* wT = (unsigned short*)(wsb + (64 << 20));    // transposed bf16 weights + relT
  unsigned short* bigh = (unsigned short*)big;

  unsigned short* wt_ff1w1 = wT + 0;        // [2048,512]
  unsigned short* wt_ff1w2 = wT + 1048576;  // [512,2048]
  unsigned short* wt_qkv   = wT + 2097152;  // [1536,512]
  unsigned short* wt_out   = wT + 2883584;  // [512,512]
  unsigned short* wt_pw1   = wT + 3145728;  // [1024,512]
  unsigned short* wt_pw2   = wT + 3670016;  // [512,512]
  unsigned short* wt_ff2w1 = wT + 3932160;  // [2048,512]
  unsigned short* wt_ff2w2 = wT + 4980736;  // [512,2048]
  unsigned short* relT     = wT + 6029312;  // [8][128][64] bf16

  const dim3 blk(256);
  const dim3 ln_grid(cM / 4);

  // ---- weight prep ----
  wconv_kernel<<<dim3(2048 / 64, 512 / 64), blk, 0, stream>>>(ff1_w1, wt_ff1w1, 512, 2048);
  wconv_kernel<<<dim3(512 / 64, 2048 / 64), blk, 0, stream>>>(ff1_w2, wt_ff1w2, 2048, 512);
  wconv_kernel<<<dim3(1536 / 64, 512 / 64), blk, 0, stream>>>(wqkv, wt_qkv, 512, 1536);
  wconv_kernel<<<dim3(512 / 64, 512 / 64), blk, 0, stream>>>(wout, wt_out, 512, 512);
  wconv_kernel<<<dim3(1024 / 64, 512 / 64), blk, 0, stream>>>(pw1_w, wt_pw1, 512, 1024);
  wconv_kernel<<<dim3(512 / 64, 512 / 64), blk, 0, stream>>>(pw2_w, wt_pw2, 512, 512);
  wconv_kernel<<<dim3(2048 / 64, 512 / 64), blk, 0, stream>>>(ff2_w1, wt_ff2w1, 512, 2048);
  wconv_kernel<<<dim3(512 / 64, 2048 / 64), blk, 0, stream>>>(ff2_w2, wt_ff2w2, 2048, 512);
  relconv_kernel<<<dim3(64), blk, 0, stream>>>(rel_pos, relT);

  // ---- FFN1 ----
  ln_kernel<false, true><<<ln_grid, blk, 0, stream>>>(x, ff1_ng, ff1_nb, nullptr, lnb);
  mgemm_kernel<true, true, 0, false, true><<<dim3(16, 64), blk, 0, stream>>>(
      lnb, wt_ff1w1, ff1_b1, nullptr, nullptr, bigh, 2048, 512);
  mgemm_kernel<true, false, 2, true, false><<<dim3(4, 64), blk, 0, stream>>>(
      bigh, wt_ff1w2, ff1_b2, x, mask, X, 512, 2048);
  // ---- MHA ----
  ln_kernel<false, true><<<ln_grid, blk, 0, stream>>>(X, mha_ng, mha_nb, nullptr, lnb);
  mgemm_kernel<false, false, 0, false, true><<<dim3(12, 64), blk, 0, stream>>>(
      lnb, wt_qkv, nullptr, nullptr, nullptr, bigh, 1536, 512);
  attn_kernel<<<dim3(cT / 64, cNH, cB), blk, 0, stream>>>(bigh, relT, mask, auxb);
  mgemm_kernel<true, false, 1, true, false><<<dim3(4, 64), blk, 0, stream>>>(
      auxb, wt_out, bout, X, mask, X, 512, 512);
  // ---- Conv module ----
  ln_kernel<false, true><<<ln_grid, blk, 0, stream>>>(X, conv_ng, conv_nb, nullptr, lnb);
  mgemm_kernel<true, false, 0, false, true><<<dim3(8, 64), blk, 0, stream>>>(
      lnb, wt_pw1, pw1_b, nullptr, nullptr, bigh, 1024, 512);
  dwconv_kernel<<<dim3(cT / 64, cD / 128, cB), blk, 0, stream>>>(
      bigh, dw_w, dw_b, bn_g, bn_b, bn_m, bn_v, auxb);
  mgemm_kernel<true, false, 1, true, false><<<dim3(4, 64), blk, 0, stream>>>(
      auxb, wt_pw2, pw2_b, X, mask, X, 512, 512);
  // ---- FFN2 ----
  ln_kernel<false, true><<<ln_grid, blk, 0, stream>>>(X, ff2_ng, ff2_nb, nullptr, lnb);
  mgemm_kernel<true, true, 0, false, true><<<dim3(16, 64), blk, 0, stream>>>(
      lnb, wt_ff2w1, ff2_b1, nullptr, nullptr, bigh, 2048, 512);
  mgemm_kernel<true, false, 2, true, false><<<dim3(4, 64), blk, 0, stream>>>(
      bigh, wt_ff2w2, ff2_b2, X, mask, X, 512, 2048);
  // ---- final LN + mask (fp32 out, in-place) ----
  ln_kernel<true, false><<<ln_grid, blk, 0, stream>>>(X, final_ng, final_nb, mask, X);
}

// Round 10
// 448.493 us; speedup vs baseline: 4.1495x; 1.0064x over previous
//
#include <hip/hip_runtime.h>

// ============================ problem constants ============================
constexpr int cB = 8, cT = 1024, cD = 512, cNH = 8, cHD = 64, cH = 127, cK = 32;
constexpr int cM = cB * cT;  // 8192 token rows
constexpr float cEPS = 1e-5f;

typedef __attribute__((ext_vector_type(8))) short bf16x8;
typedef __attribute__((ext_vector_type(4))) float f32x4;
typedef __attribute__((ext_vector_type(8))) unsigned short u16x8;

__device__ __forceinline__ float sigm_(float x) { return 1.0f / (1.0f + __expf(-x)); }

__device__ __forceinline__ unsigned short f2bf(float f) {
  union { float f; unsigned int u; } v; v.f = f;
  unsigned int r = v.u + 0x7fffu + ((v.u >> 16) & 1u);  // RNE
  return (unsigned short)(r >> 16);
}
__device__ __forceinline__ float bf2f(unsigned short u) {
  union { unsigned int u; float f; } v; v.u = (unsigned int)u << 16;
  return v.f;
}

__device__ __forceinline__ void gload_lds16(const void* g, void* l) {
  __builtin_amdgcn_global_load_lds(
      (const __attribute__((address_space(1))) void*)g,
      (__attribute__((address_space(3))) void*)l, 16, 0, 0);
}

// ============================ LayerNorm (fp32 in, bf16 or fp32 out) ============================
template<bool MASKOUT, bool OUTBF>
__global__ __launch_bounds__(256) void ln_kernel(
    const float* __restrict__ in, const float* __restrict__ gw,
    const float* __restrict__ bw, const unsigned char* __restrict__ mask,
    void* __restrict__ outv) {
  int row = blockIdx.x * 4 + (threadIdx.x >> 6);
  int lane = threadIdx.x & 63;
  const float4* x4 = reinterpret_cast<const float4*>(in + (size_t)row * cD);
  float4 v0 = x4[2 * lane];
  float4 v1 = x4[2 * lane + 1];
  float s = v0.x + v0.y + v0.z + v0.w + v1.x + v1.y + v1.z + v1.w;
  float q = v0.x * v0.x + v0.y * v0.y + v0.z * v0.z + v0.w * v0.w +
            v1.x * v1.x + v1.y * v1.y + v1.z * v1.z + v1.w * v1.w;
#pragma unroll
  for (int m = 1; m < 64; m <<= 1) {
    s += __shfl_xor(s, m);
    q += __shfl_xor(q, m);
  }
  float mean = s * (1.0f / cD);
  float var = q * (1.0f / cD) - mean * mean;
  float rs = rsqrtf(var + cEPS);
  float keep = 1.0f;
  if (MASKOUT) keep = mask[row] ? 0.0f : 1.0f;
  const float4* g4 = reinterpret_cast<const float4*>(gw);
  const float4* b4 = reinterpret_cast<const float4*>(bw);
  float4 ga = g4[2 * lane], gb = g4[2 * lane + 1];
  float4 ba = b4[2 * lane], bb = b4[2 * lane + 1];
  float o[8];
  o[0] = ((v0.x - mean) * rs * ga.x + ba.x) * keep;
  o[1] = ((v0.y - mean) * rs * ga.y + ba.y) * keep;
  o[2] = ((v0.z - mean) * rs * ga.z + ba.z) * keep;
  o[3] = ((v0.w - mean) * rs * ga.w + ba.w) * keep;
  o[4] = ((v1.x - mean) * rs * gb.x + bb.x) * keep;
  o[5] = ((v1.y - mean) * rs * gb.y + bb.y) * keep;
  o[6] = ((v1.z - mean) * rs * gb.z + bb.z) * keep;
  o[7] = ((v1.w - mean) * rs * gb.w + bb.w) * keep;
  if (OUTBF) {
    u16x8 p;
#pragma unroll
    for (int i = 0; i < 8; ++i) p[i] = f2bf(o[i]);
    *reinterpret_cast<u16x8*>((unsigned short*)outv + (size_t)row * cD + lane * 8) = p;
  } else {
    float4 o0 = {o[0], o[1], o[2], o[3]}, o1 = {o[4], o[5], o[6], o[7]};
    float4* o4 = reinterpret_cast<float4*>((float*)outv + (size_t)row * cD);
    o4[2 * lane] = o0;
    o4[2 * lane + 1] = o1;
  }
}

// ============================ weight fp32[K,N] -> bf16 W^T[N,K] ============================
__global__ __launch_bounds__(256) void wconv_kernel(
    const float* __restrict__ W, unsigned short* __restrict__ WT, int K, int N) {
  __shared__ float t[64][65];
  const int n0 = blockIdx.x * 64, k0 = blockIdx.y * 64;
  const int tx = threadIdx.x & 63, ty = threadIdx.x >> 6;
#pragma unroll
  for (int i = 0; i < 16; ++i) {
    int kr = ty * 16 + i;
    t[kr][tx] = W[(size_t)(k0 + kr) * N + n0 + tx];
  }
  __syncthreads();
#pragma unroll
  for (int i = 0; i < 16; ++i) {
    int nr = ty * 16 + i;
    WT[(size_t)(n0 + nr) * K + k0 + tx] = f2bf(t[tx][nr]);
  }
}

// ============================ rel_pos fp32 [128][8][64] -> bf16 relT [8][128][64] ============================
__global__ __launch_bounds__(256) void relconv_kernel(
    const float* __restrict__ rel, unsigned short* __restrict__ relT) {
  int flat = (blockIdx.x * 256 + threadIdx.x) * 4;  // 65536 elems total
  int h = flat >> 13, rem = flat & 8191;
  int p = rem >> 6, d = rem & 63;
  float4 v = *reinterpret_cast<const float4*>(rel + ((size_t)p * cNH + h) * cHD + d);
  ushort4 o = {f2bf(v.x), f2bf(v.y), f2bf(v.z), f2bf(v.w)};
  *reinterpret_cast<ushort4*>(relT + flat) = o;
}

// ============================ bf16 MFMA GEMM (2-phase dbuf + XCD swizzle) ============================
// C[M,N] = act(A[M,K]bf16 @ W[K,N] + bias) [+res] [*mask]; W given as WT[N,K]bf16.
// 128x128 tile, BK=32, 4 waves (2x2 of 64x64). Bijective XCD swizzle (grids are %8==0):
// hardware round-robins dispatch index d onto XCD d%8; new_id=(d&7)*(nwg/8)+(d>>3)
// gives each XCD a CONTIGUOUS chunk = complete A-row-panels -> each A panel fetched by
// exactly one XCD L2 (round-9 FETCH showed 8x A re-fetch, 75.8 MB vs ~10 ideal).
template<bool BIAS, bool SILU, int RES, bool MASK, bool OUTBF>
__global__ __launch_bounds__(256) void mgemm_kernel(
    const unsigned short* __restrict__ A, const unsigned short* __restrict__ WT,
    const float* __restrict__ bias, const float* __restrict__ res,
    const unsigned char* __restrict__ mask, void* __restrict__ outv,
    int N, int K) {
  __shared__ unsigned short ldsA[2][4096];  // 2 x 128x32 bf16
  __shared__ unsigned short ldsB[2][4096];
  const int tid = threadIdx.x, lane = tid & 63, wid = tid >> 6;
  int id = blockIdx.y * gridDim.x + blockIdx.x;
  const int nwg = gridDim.x * gridDim.y;
  id = (id & 7) * (nwg >> 3) + (id >> 3);
  const int m0 = (id / gridDim.x) * 128, n0 = (id % gridDim.x) * 128;
  const int wr = wid >> 1, wc = wid & 1;  // wave's 64x64 quadrant

  const int sr = wid * 32 + (lane >> 2);
  const int sc = (lane & 3) * 8;  // element offset within k-window (8 bf16 = 16B)
  const unsigned short* a0 = A + (size_t)(m0 + sr) * K + sc;
  const unsigned short* a1 = A + (size_t)(m0 + sr + 16) * K + sc;
  const unsigned short* b0 = WT + (size_t)(n0 + sr) * K + sc;
  const unsigned short* b1 = WT + (size_t)(n0 + sr + 16) * K + sc;
  const int wof = wid * 1024;  // LDS base (shorts) for this wave's 32 rows

  f32x4 acc[4][4] = {};

  const int fr = lane & 15, fq = lane >> 4;  // fragment row, k-chunk
  const int fco = fq * 8;

  const int nt = K >> 5;
  // prologue: stage tile 0 into buffer 0
  gload_lds16(a0, &ldsA[0][wof]);
  gload_lds16(a1, &ldsA[0][wof + 512]);
  gload_lds16(b0, &ldsB[0][wof]);
  gload_lds16(b1, &ldsB[0][wof + 512]);
  asm volatile("s_waitcnt vmcnt(0)" ::: "memory");
  __syncthreads();

  int cur = 0;
  for (int t = 0; t < nt; ++t) {
    if (t + 1 < nt) {  // issue next-tile staging first; latency hides under MFMA
      const int k1 = (t + 1) << 5;
      gload_lds16(a0 + k1, &ldsA[cur ^ 1][wof]);
      gload_lds16(a1 + k1, &ldsA[cur ^ 1][wof + 512]);
      gload_lds16(b0 + k1, &ldsB[cur ^ 1][wof]);
      gload_lds16(b1 + k1, &ldsB[cur ^ 1][wof + 512]);
    }
    bf16x8 af[4], bfr[4];
#pragma unroll
    for (int f = 0; f < 4; ++f) {
      af[f] = *reinterpret_cast<const bf16x8*>(&ldsA[cur][(wr * 64 + f * 16 + fr) * 32 + fco]);
      bfr[f] = *reinterpret_cast<const bf16x8*>(&ldsB[cur][(wc * 64 + f * 16 + fr) * 32 + fco]);
    }
#pragma unroll
    for (int i = 0; i < 4; ++i)
#pragma unroll
      for (int j = 0; j < 4; ++j)
        acc[i][j] = __builtin_amdgcn_mfma_f32_16x16x32_bf16(af[i], bfr[j], acc[i][j], 0, 0, 0);
    asm volatile("s_waitcnt vmcnt(0)" ::: "memory");
    __syncthreads();
    cur ^= 1;
  }

#pragma unroll
  for (int fm = 0; fm < 4; ++fm) {
#pragma unroll
    for (int fn = 0; fn < 4; ++fn) {
      const int cn = n0 + wc * 64 + fn * 16 + fr;
      const float bv = BIAS ? bias[cn] : 0.0f;
#pragma unroll
      for (int j = 0; j < 4; ++j) {
        const int m = m0 + wr * 64 + fm * 16 + fq * 4 + j;
        float t = acc[fm][fn][j] + bv;
        if (SILU) t = t * sigm_(t);
        if (RES == 1) t = res[(size_t)m * N + cn] + t;
        if (RES == 2) t = res[(size_t)m * N + cn] + 0.5f * t;
        if (MASK) t = mask[m] ? 0.0f : t;
        if (OUTBF) ((unsigned short*)outv)[(size_t)m * N + cn] = f2bf(t);
        else       ((float*)outv)[(size_t)m * N + cn] = t;
      }
    }
  }
}

// ============================ banded MFMA attention (bf16 qkv in, bf16 out) ============================
// Block = (b, h, 64 queries) = 4 waves x 16-q tiles; 256 threads. XCD-swizzled so each
// XCD owns one full batch's (h, q-tile) plane -> qkv[b] fetched once per XCD L2.
__global__ __launch_bounds__(256) void attn_kernel(
    const unsigned short* __restrict__ qkv, const unsigned short* __restrict__ relT,
    const unsigned char* __restrict__ mask, unsigned short* __restrict__ out) {
  __shared__ alignas(16) unsigned short KV[192 * 72];  // K [slot][72]; later VT [64][200]
  __shared__ alignas(16) float QRu[4][16 * 132];       // per-wave QR f32; later P bf16 [16][200]
  __shared__ unsigned char msk[192];
  const int tid = threadIdx.x;
  int id = (blockIdx.z * gridDim.y + blockIdx.y) * gridDim.x + blockIdx.x;
  const int nwg = gridDim.x * gridDim.y * gridDim.z;
  id = (id & 7) * (nwg >> 3) + (id >> 3);
  const int qt = id % gridDim.x;
  const int rest = id / gridDim.x;
  const int h = rest % gridDim.y;
  const int b = rest / gridDim.y;
  const int q0 = qt * 64;

  for (int s = tid; s < 192; s += 256) {
    int t = q0 - 127 + s;
    msk[s] = (t < 0 || t >= cT) ? 1 : mask[(size_t)b * cT + t];
  }
  for (int i = tid; i < 1536; i += 256) {  // K: 192 rows x 8 chunks
    int row = i >> 3, ch = i & 7;
    int t = q0 - 127 + row;
    bf16x8 v = {};
    if (t >= 0 && t < cT)
      v = *reinterpret_cast<const bf16x8*>(qkv + (size_t)(b * cT + t) * 1536 + 512 + h * 64 + ch * 8);
    *reinterpret_cast<bf16x8*>(KV + row * 72 + ch * 8) = v;
  }
  __syncthreads();

  const int w = tid >> 6, lane = tid & 63;
  const int fr = lane & 15, fq = lane >> 4;

  // Q A-frags in registers (q row = q0 + w*16 + fr)
  const unsigned short* qp = qkv + (size_t)(b * cT + q0 + w * 16 + fr) * 1536 + h * 64;
  bf16x8 qf0 = *reinterpret_cast<const bf16x8*>(qp + fq * 8);
  bf16x8 qf1 = *reinterpret_cast<const bf16x8*>(qp + 32 + fq * 8);

  // S = Q.K^T : 12 key-frags x (K=64 -> 2 mfma)
  f32x4 sacc[12] = {};
#pragma unroll
  for (int f = 0; f < 12; ++f) {
    const unsigned short* kb = KV + (f * 16 + fr) * 72;
    sacc[f] = __builtin_amdgcn_mfma_f32_16x16x32_bf16(qf0, *reinterpret_cast<const bf16x8*>(kb + fq * 8), sacc[f], 0, 0, 0);
    sacc[f] = __builtin_amdgcn_mfma_f32_16x16x32_bf16(qf1, *reinterpret_cast<const bf16x8*>(kb + 32 + fq * 8), sacc[f], 0, 0, 0);
  }
  // QR = Q.rel^T : 8 p-frags x 2 (B-frags from global relT, L2-resident)
  f32x4 qr[8] = {};
  const unsigned short* rT = relT + (size_t)h * 8192;
#pragma unroll
  for (int fp = 0; fp < 8; ++fp) {
    const unsigned short* rb = rT + (fp * 16 + fr) * 64;
    qr[fp] = __builtin_amdgcn_mfma_f32_16x16x32_bf16(qf0, *reinterpret_cast<const bf16x8*>(rb + fq * 8), qr[fp], 0, 0, 0);
    qr[fp] = __builtin_amdgcn_mfma_f32_16x16x32_bf16(qf1, *reinterpret_cast<const bf16x8*>(rb + 32 + fq * 8), qr[fp], 0, 0, 0);
  }
  float* QR = QRu[w];
#pragma unroll
  for (int fp = 0; fp < 8; ++fp)
#pragma unroll
    for (int j = 0; j < 4; ++j)
      QR[(fq * 4 + j) * 132 + fp * 16 + fr] = qr[fp][j];
  asm volatile("s_waitcnt lgkmcnt(0)" ::: "memory");
  __builtin_amdgcn_sched_barrier(0);

  // gather rel + band/pad mask; softmax over 192 slots per q-row
  float mrow[4] = {-3e38f, -3e38f, -3e38f, -3e38f};
#pragma unroll
  for (int f = 0; f < 12; ++f) {
    int slot = f * 16 + fr;
#pragma unroll
    for (int j = 0; j < 4; ++j) {
      int row = fq * 4 + j;
      int pidx = w * 16 + row + 127 - slot;  // q - t
      float v = -1e30f;
      if ((unsigned)pidx <= 127u && !msk[slot])
        v = (sacc[f][j] + QR[row * 132 + pidx]) * 0.125f;
      sacc[f][j] = v;
      mrow[j] = fmaxf(mrow[j], v);
    }
  }
#pragma unroll
  for (int j = 0; j < 4; ++j) {
    float m = mrow[j];
    m = fmaxf(m, __shfl_xor(m, 1));
    m = fmaxf(m, __shfl_xor(m, 2));
    m = fmaxf(m, __shfl_xor(m, 4));
    m = fmaxf(m, __shfl_xor(m, 8));
    mrow[j] = m;
  }
  float srow[4] = {0.f, 0.f, 0.f, 0.f};
#pragma unroll
  for (int f = 0; f < 12; ++f)
#pragma unroll
    for (int j = 0; j < 4; ++j) {
      float p = __expf(sacc[f][j] - mrow[j]);
      sacc[f][j] = p;
      srow[j] += p;
    }
#pragma unroll
  for (int j = 0; j < 4; ++j) {
    float s = srow[j];
    s += __shfl_xor(s, 1);
    s += __shfl_xor(s, 2);
    s += __shfl_xor(s, 4);
    s += __shfl_xor(s, 8);
    srow[j] = 1.0f / s;
  }
  // P -> bf16 [16][200], aliases this wave's QR region (all QR reads done above)
  unsigned short* P = reinterpret_cast<unsigned short*>(QRu[w]);
#pragma unroll
  for (int f = 0; f < 12; ++f)
#pragma unroll
    for (int j = 0; j < 4; ++j)
      P[(fq * 4 + j) * 200 + f * 16 + fr] = f2bf(sacc[f][j] * srow[j]);

  // all waves must finish reading K before V overwrites KV
  __syncthreads();
  {
    unsigned short* VT = KV;  // [64 d][200 slots]
    for (int i = tid; i < 1536; i += 256) {
      int row = i >> 3, ch = i & 7;
      int t = q0 - 127 + row;
      u16x8 v = {};
      if (t >= 0 && t < cT)
        v = *reinterpret_cast<const u16x8*>(qkv + (size_t)(b * cT + t) * 1536 + 1024 + h * 64 + ch * 8);
#pragma unroll
      for (int e = 0; e < 8; ++e) VT[(ch * 8 + e) * 200 + row] = v[e];
    }
  }
  __syncthreads();

  // PV: A = P [q][slot], B = VT [d][slot]; K = 192 -> 6 k-steps
  f32x4 oacc[4] = {};
  const unsigned short* VT = KV;
#pragma unroll
  for (int ks = 0; ks < 6; ++ks) {
    bf16x8 pa = *reinterpret_cast<const bf16x8*>(P + fr * 200 + ks * 32 + fq * 8);
#pragma unroll
    for (int fn = 0; fn < 4; ++fn)
      oacc[fn] = __builtin_amdgcn_mfma_f32_16x16x32_bf16(
          pa, *reinterpret_cast<const bf16x8*>(VT + (fn * 16 + fr) * 200 + ks * 32 + fq * 8), oacc[fn], 0, 0, 0);
  }
#pragma unroll
  for (int fn = 0; fn < 4; ++fn)
#pragma unroll
    for (int j = 0; j < 4; ++j)
      out[(size_t)(b * cT + q0 + w * 16 + fq * 4 + j) * cD + h * 64 + fn * 16 + fr] = f2bf(oacc[fn][j]);
}

// ============================ GLU + depthwise conv + BN + SiLU (bf16 in, bf16 out) ============================
__global__ __launch_bounds__(256) void dwconv_kernel(
    const unsigned short* __restrict__ pw1out, const float* __restrict__ dww,
    const float* __restrict__ dwb, const float* __restrict__ bng,
    const float* __restrict__ bnb, const float* __restrict__ bnm,
    const float* __restrict__ bnv, unsigned short* __restrict__ out) {
  constexpr int TT = 64, DD = 128, PAD = cK - 1;
  __shared__ alignas(16) float g_lds[TT + PAD][DD];
  const int b = blockIdx.z, d0 = blockIdx.y * DD, t0 = blockIdx.x * TT;
  const int tid = threadIdx.x;

  for (int f = tid; f < (TT + PAD) * (DD / 4); f += 256) {
    int row = f >> 5, c4 = (f & 31) * 4;
    int t = t0 - PAD + row;
    float4 val = {0.f, 0.f, 0.f, 0.f};
    if (t >= 0) {
      const unsigned short* base = pw1out + (size_t)(b * cT + t) * (2 * cD) + d0 + c4;
      ushort4 a = *reinterpret_cast<const ushort4*>(base);
      ushort4 g = *reinterpret_cast<const ushort4*>(base + cD);
      val.x = bf2f(a.x) * sigm_(bf2f(g.x));
      val.y = bf2f(a.y) * sigm_(bf2f(g.y));
      val.z = bf2f(a.z) * sigm_(bf2f(g.z));
      val.w = bf2f(a.w) * sigm_(bf2f(g.w));
    }
    *reinterpret_cast<float4*>(&g_lds[row][c4]) = val;
  }
  __syncthreads();

  const int dl = tid & 127, tg = tid >> 7;
  const int d = d0 + dl;
  float w[cK];
  const float4* w4 = reinterpret_cast<const float4*>(dww + (size_t)d * cK);
#pragma unroll
  for (int i = 0; i < cK / 4; ++i) {
    float4 t4 = w4[i];
    w[i * 4 + 0] = t4.x; w[i * 4 + 1] = t4.y; w[i * 4 + 2] = t4.z; w[i * 4 + 3] = t4.w;
  }
  const float bias = dwb[d];
  const float scale = bng[d] * rsqrtf(bnv[d] + cEPS);
  const float shift = bnb[d] - bnm[d] * scale;
#pragma unroll 4
  for (int i = 0; i < 32; ++i) {
    int tl = tg * 32 + i;
    float acc = bias;
#pragma unroll
    for (int k = 0; k < cK; ++k) acc += w[k] * g_lds[tl + k][dl];
    float v = acc * scale + shift;
    v = v * sigm_(v);
    out[(size_t)(b * cT + t0 + tl) * cD + d] = f2bf(v);
  }
}

// ============================ launch ============================
extern "C" void kernel_launch(void* const* d_in, const int* in_sizes, int n_in,
                              void* d_out, int out_size, void* d_ws, size_t ws_size,
                              hipStream_t stream) {
  const float* x = (const float*)d_in[0];
  const unsigned char* mask = (const unsigned char*)d_in[1];
  const float* ff1_ng = (const float*)d_in[2];
  const float* ff1_nb = (const float*)d_in[3];
  const float* ff1_w1 = (const float*)d_in[4];
  const float* ff1_b1 = (const float*)d_in[5];
  const float* ff1_w2 = (const float*)d_in[6];
  const float* ff1_b2 = (const float*)d_in[7];
  const float* mha_ng = (const float*)d_in[8];
  const float* mha_nb = (const float*)d_in[9];
  const float* wqkv = (const float*)d_in[10];
  const float* wout = (const float*)d_in[11];
  const float* bout = (const float*)d_in[12];
  const float* rel_pos = (const float*)d_in[13];
  const float* conv_ng = (const float*)d_in[14];
  const float* conv_nb = (const float*)d_in[15];
  const float* pw1_w = (const float*)d_in[16];
  const float* pw1_b = (const float*)d_in[17];
  const float* dw_w = (const float*)d_in[18];
  const float* dw_b = (const float*)d_in[19];
  const float* bn_g = (const float*)d_in[20];
  const float* bn_b = (const float*)d_in[21];
  const float* bn_m = (const float*)d_in[22];
  const float* bn_v = (const float*)d_in[23];
  const float* pw2_w = (const float*)d_in[24];
  const float* pw2_b = (const float*)d_in[25];
  const float* ff2_ng = (const float*)d_in[26];
  const float* ff2_nb = (const float*)d_in[27];
  const float* ff2_w1 = (const float*)d_in[28];
  const float* ff2_b1 = (const float*)d_in[29];
  const float* ff2_w2 = (const float*)d_in[30];
  const float* ff2_b2 = (const float*)d_in[31];
  const float* final_ng = (const float*)d_in[32];
  const float* final_nb = (const float*)d_in[33];

  float* X = (float*)d_out;  // fp32 residual stream
  char* wsb = (char*)d_ws;
  unsigned short* lnb = (unsigned short*)wsb;                  // [8192,512] bf16, 8 MB
  unsigned short* auxb = (unsigned short*)(wsb + (8 << 20));   // [8192,512] bf16, 8 MB
  char* big = wsb + (16 << 20);                                // qkv bf16 / ffn-mid bf16 / pw1out bf16
  unsigned short* wT = (unsigned short*)(wsb + (64 << 20));    // transposed bf16 weights + relT
  unsigned short* bigh = (unsigned short*)big;

  unsigned short* wt_ff1w1 = wT + 0;        // [2048,512]
  unsigned short* wt_ff1w2 = wT + 1048576;  // [512,2048]
  unsigned short* wt_qkv   = wT + 2097152;  // [1536,512]
  unsigned short* wt_out   = wT + 2883584;  // [512,512]
  unsigned short* wt_pw1   = wT + 3145728;  // [1024,512]
  unsigned short* wt_pw2   = wT + 3670016;  // [512,512]
  unsigned short* wt_ff2w1 = wT + 3932160;  // [2048,512]
  unsigned short* wt_ff2w2 = wT + 4980736;  // [512,2048]
  unsigned short* relT     = wT + 6029312;  // [8][128][64] bf16

  const dim3 blk(256);
  const dim3 ln_grid(cM / 4);

  // ---- weight prep ----
  wconv_kernel<<<dim3(2048 / 64, 512 / 64), blk, 0, stream>>>(ff1_w1, wt_ff1w1, 512, 2048);
  wconv_kernel<<<dim3(512 / 64, 2048 / 64), blk, 0, stream>>>(ff1_w2, wt_ff1w2, 2048, 512);
  wconv_kernel<<<dim3(1536 / 64, 512 / 64), blk, 0, stream>>>(wqkv, wt_qkv, 512, 1536);
  wconv_kernel<<<dim3(512 / 64, 512 / 64), blk, 0, stream>>>(wout, wt_out, 512, 512);
  wconv_kernel<<<dim3(1024 / 64, 512 / 64), blk, 0, stream>>>(pw1_w, wt_pw1, 512, 1024);
  wconv_kernel<<<dim3(512 / 64, 512 / 64), blk, 0, stream>>>(pw2_w, wt_pw2, 512, 512);
  wconv_kernel<<<dim3(2048 / 64, 512 / 64), blk, 0, stream>>>(ff2_w1, wt_ff2w1, 512, 2048);
  wconv_kernel<<<dim3(512 / 64, 2048 / 64), blk, 0, stream>>>(ff2_w2, wt_ff2w2, 2048, 512);
  relconv_kernel<<<dim3(64), blk, 0, stream>>>(rel_pos, relT);

  // ---- FFN1 ----
  ln_kernel<false, true><<<ln_grid, blk, 0, stream>>>(x, ff1_ng, ff1_nb, nullptr, lnb);
  mgemm_kernel<true, true, 0, false, true><<<dim3(16, 64), blk, 0, stream>>>(
      lnb, wt_ff1w1, ff1_b1, nullptr, nullptr, bigh, 2048, 512);
  mgemm_kernel<true, false, 2, true, false><<<dim3(4, 64), blk, 0, stream>>>(
      bigh, wt_ff1w2, ff1_b2, x, mask, X, 512, 2048);
  // ---- MHA ----
  ln_kernel<false, true><<<ln_grid, blk, 0, stream>>>(X, mha_ng, mha_nb, nullptr, lnb);
  mgemm_kernel<false, false, 0, false, true><<<dim3(12, 64), blk, 0, stream>>>(
      lnb, wt_qkv, nullptr, nullptr, nullptr, bigh, 1536, 512);
  attn_kernel<<<dim3(cT / 64, cNH, cB), blk, 0, stream>>>(bigh, relT, mask, auxb);
  mgemm_kernel<true, false, 1, true, false><<<dim3(4, 64), blk, 0, stream>>>(
      auxb, wt_out, bout, X, mask, X, 512, 512);
  // ---- Conv module ----
  ln_kernel<false, true><<<ln_grid, blk, 0, stream>>>(X, conv_ng, conv_nb, nullptr, lnb);
  mgemm_kernel<true, false, 0, false, true><<<dim3(8, 64), blk, 0, stream>>>(
      lnb, wt_pw1, pw1_b, nullptr, nullptr, bigh, 1024, 512);
  dwconv_kernel<<<dim3(cT / 64, cD / 128, cB), blk, 0, stream>>>(
      bigh, dw_w, dw_b, bn_g, bn_b, bn_m, bn_v, auxb);
  mgemm_kernel<true, false, 1, true, false><<<dim3(4, 64), blk, 0, stream>>>(
      auxb, wt_pw2, pw2_b, X, mask, X, 512, 512);
  // ---- FFN2 ----
  ln_kernel<false, true><<<ln_grid, blk, 0, stream>>>(X, ff2_ng, ff2_nb, nullptr, lnb);
  mgemm_kernel<true, true, 0, false, true><<<dim3(16, 64), blk, 0, stream>>>(
      lnb, wt_ff2w1, ff2_b1, nullptr, nullptr, bigh, 2048, 512);
  mgemm_kernel<true, false, 2, true, false><<<dim3(4, 64), blk, 0, stream>>>(
      bigh, wt_ff2w2, ff2_b2, X, mask, X, 512, 2048);
  // ---- final LN + mask (fp32 out, in-place) ----
  ln_kernel<true, false><<<ln_grid, blk, 0, stream>>>(X, final_ng, final_nb, mask, X);
}